// Round 1
// baseline (1722.072 us; speedup 1.0000x reference)
//
#include <hip/hip_runtime.h>
#include <math.h>

namespace {
constexpr int T = 64, D = 1024, V = 1024;
constexpr float G1 = 5.0f, G2 = 5.0f, G3 = 10.0f;
constexpr int RT1 = 256;   // pass-1 r tile
constexpr int KT  = 32;    // pass-1 k tile
constexpr int DT2 = 256;   // pass-2 d tile
constexpr int RK2 = 32;    // pass-2 r chunk
constexpr int SIMP = 260;  // padded row stride for big LDS tile
// workspace layout (floats)
constexpr int WS_S    = 0;       // 256 scores
constexpr int WS_BETA = 256;     // 16 * 64*16 diagonal betas
constexpr int WS_W    = 32768;   // W slots, 65536 floats each
constexpr int WPP     = T * V;   // 65536
}

// One workgroup computes the full matching score for pair (a = v index, b = e index).
__global__ __launch_bounds__(512)
void sim_pair_kernel(const float* __restrict__ E, const float* __restrict__ Vb,
                     float* __restrict__ ws, int pair_base, int swizzle)
{
    __shared__ float ldsA[KT * 64];    // 8 KB : e k-tile [k][t] / W chunk [r][t]
    __shared__ float ldsB[KT * RT1];   // 32 KB: v tiles / tail e tile
    __shared__ float ldsC[64 * SIMP];  // 65 KB: sim tile / e d-tile / e_prime
    __shared__ float s_Z[64];
    __shared__ float s_bnum[64 * 16];
    __shared__ float s_bsum[16];
    __shared__ float s_beta[64 * 16];
    __shared__ float s_redA[512];
    __shared__ float s_redB[512];
    __shared__ float s_dotve[64];
    __shared__ float s_ssvt[64];
    __shared__ float s_sse[64];
    __shared__ float s_ssep[16];
    __shared__ float s_ref[16];
    __shared__ float s_scal[2];

    const int tid = threadIdx.x;
    int p;
    if (swizzle) {  // keep the two blocks sharing v_a on one XCD (round-robin dispatch)
        int i = blockIdx.x;
        int xcd = i & 7, slot = i >> 3;
        int aa = xcd + 8 * (slot & 1);
        int bb = slot >> 1;
        p = aa * 16 + bb;
    } else {
        p = pair_base + blockIdx.x;
    }
    const int a = p >> 4, b = p & 15;
    const float* __restrict__ e = E + (size_t)b * T * D;
    const float* __restrict__ v = Vb + (size_t)a * V * D;
    float* __restrict__ Wg = ws + WS_W + (size_t)blockIdx.x * WPP;

    const int ty = tid >> 5;   // 0..15
    const int tx = tid & 31;   // 0..31
    const int t0 = ty << 2;

    for (int i = tid; i < 64; i += 512) { s_Z[i] = 0.f; s_dotve[i] = 0.f; s_ssvt[i] = 0.f; s_sse[i] = 0.f; }
    if (tid < 16) { s_ssep[tid] = 0.f; s_ref[tid] = 0.f; }
    __syncthreads();

    // ---------------- Pass 1: sim -> nsim -> W, Z, bnum ----------------
    for (int rt = 0; rt < V / RT1; ++rt) {
        const int r0 = rt * RT1;
        float acc[4][8];
#pragma unroll
        for (int i = 0; i < 4; ++i)
#pragma unroll
            for (int j = 0; j < 8; ++j) acc[i][j] = 0.f;

        for (int kt = 0; kt < D / KT; ++kt) {
            const int k0 = kt * KT;
            {   // stage e k-tile transposed [k][t]
                const int trow = tid >> 3, k4 = (tid & 7) << 2;
                float4 f = *(const float4*)(e + (size_t)trow * D + k0 + k4);
                ldsA[(k4 + 0) * 64 + trow] = f.x;
                ldsA[(k4 + 1) * 64 + trow] = f.y;
                ldsA[(k4 + 2) * 64 + trow] = f.z;
                ldsA[(k4 + 3) * 64 + trow] = f.w;
            }
            {   // stage v tile transposed [k][r]
                const int k4 = (tid & 7) << 2;
#pragma unroll
                for (int it = 0; it < 4; ++it) {
                    const int rr = (tid >> 3) + (it << 6);
                    float4 f = *(const float4*)(v + (size_t)(r0 + rr) * D + k0 + k4);
                    ldsB[(k4 + 0) * RT1 + rr] = f.x;
                    ldsB[(k4 + 1) * RT1 + rr] = f.y;
                    ldsB[(k4 + 2) * RT1 + rr] = f.z;
                    ldsB[(k4 + 3) * RT1 + rr] = f.w;
                }
            }
            __syncthreads();
#pragma unroll
            for (int k = 0; k < KT; ++k) {
                float4 ef = *(const float4*)&ldsA[k * 64 + t0];
                float4 v0 = *(const float4*)&ldsB[k * RT1 + (tx << 3)];
                float4 v1 = *(const float4*)&ldsB[k * RT1 + (tx << 3) + 4];
                float ar[4] = {ef.x, ef.y, ef.z, ef.w};
                float br[8] = {v0.x, v0.y, v0.z, v0.w, v1.x, v1.y, v1.z, v1.w};
#pragma unroll
                for (int i = 0; i < 4; ++i)
#pragma unroll
                    for (int j = 0; j < 8; ++j)
                        acc[i][j] = fmaf(ar[i], br[j], acc[i][j]);
            }
            __syncthreads();
        }
        // sim tile -> ldsC [t][c]
#pragma unroll
        for (int i = 0; i < 4; ++i)
#pragma unroll
            for (int j = 0; j < 8; ++j)
                ldsC[(t0 + i) * SIMP + (tx << 3) + j] = acc[i][j];
        __syncthreads();

        // column softmax over t (axis=0 of sim)
        {
            const int col = tid & 255, q = tid >> 8;
            float mx = -1e30f;
            for (int t = q * 32; t < q * 32 + 32; ++t)
                mx = fmaxf(mx, ldsC[t * SIMP + col]);
            s_redA[q * 256 + col] = mx;
            __syncthreads();
            const float cm = fmaxf(s_redA[col], s_redA[256 + col]);
            float sm = 0.f;
            for (int t = q * 32; t < q * 32 + 32; ++t) {
                float ex = expf(ldsC[t * SIMP + col] - cm);
                ldsC[t * SIMP + col] = ex;
                sm += ex;
            }
            s_redB[q * 256 + col] = sm;
            __syncthreads();
            const float cs = s_redB[col] + s_redB[256 + col];
            for (int t = q * 32; t < q * 32 + 32; ++t)
                ldsC[t * SIMP + col] = ldsC[t * SIMP + col] / cs;
        }
        __syncthreads();

        // row phase: se = exp(nsim), W = exp(G1*nsim) = se^5; Z and block sums
        {
            const int trow = tid >> 3, cq = tid & 7;
            float zp = 0.f, sp = 0.f;
            for (int c = cq * 32; c < cq * 32 + 32; ++c) {
                const float ns = ldsC[trow * SIMP + c];
                const float se = expf(ns);
                float w = se * se; w = w * w; w = w * se;
                ldsC[trow * SIMP + c] = w;
                zp += w; sp += se;
            }
            s_redA[cq * 64 + trow] = zp;
            s_redB[cq * 64 + trow] = sp;
        }
        __syncthreads();
        if (tid < 64) {
            float z = 0.f;
            for (int cq = 0; cq < 8; ++cq) z += s_redA[cq * 64 + tid];
            s_Z[tid] += z;
        }
        if (tid < 256) {   // bnum[t][m], tile rt covers m = 4*rt .. 4*rt+3
            const int trow = tid & 63, ml = tid >> 6;
            s_bnum[trow * 16 + rt * 4 + ml] =
                s_redB[(2 * ml) * 64 + trow] + s_redB[(2 * ml + 1) * 64 + trow];
        }
        __syncthreads();
        // W tile -> global, transposed [r][t] (coalesced along t)
        for (int i = 0; i < 32; ++i) {
            const int idx = tid + 512 * i;
            const int trow = idx & 63, c = idx >> 6;
            Wg[(size_t)(r0 + c) * 64 + trow] = ldsC[trow * SIMP + c];
        }
        __syncthreads();
    }

    // beta[t][m] = bnum / bsum
    if (tid < 16) {
        float s = 0.f;
        for (int t = 0; t < 64; ++t) s += s_bnum[t * 16 + tid];
        s_bsum[tid] = s;
    }
    __syncthreads();
    for (int idx = tid; idx < 1024; idx += 512)
        s_beta[idx] = s_bnum[idx] / s_bsum[idx & 15];
    __syncthreads();
    if (a == b) {
        for (int idx = tid; idx < 1024; idx += 512)
            ws[WS_BETA + a * 1024 + idx] = s_beta[idx];
    }

    // ---------------- Pass 2: v_tilde = (W @ v)/Z, fused cos1 ----------------
    for (int dt = 0; dt < D / DT2; ++dt) {
        const int d0 = dt * DT2;
        {   // e d-tile [t][c] into ldsC (needed only in epilogue)
            const int trow = tid >> 3, cb = (tid & 7) << 2;
#pragma unroll
            for (int it = 0; it < 8; ++it) {
                const int c = cb + (it << 5);
                *(float4*)&ldsC[trow * SIMP + c] =
                    *(const float4*)(e + (size_t)trow * D + d0 + c);
            }
        }
        float acc[4][8];
#pragma unroll
        for (int i = 0; i < 4; ++i)
#pragma unroll
            for (int j = 0; j < 8; ++j) acc[i][j] = 0.f;

        for (int rk = 0; rk < V / RK2; ++rk) {
            const int rr0 = rk * RK2;
            {   // stage W chunk [r][t] (coalesced)
                const int r = tid >> 4, t4 = (tid & 15) << 2;
                *(float4*)&ldsA[r * 64 + t4] =
                    *(const float4*)(Wg + (size_t)(rr0 + r) * 64 + t4);
            }
            {   // stage v chunk [r][d] (natural layout, coalesced)
                const int c4 = (tid & 63) << 2;
#pragma unroll
                for (int it = 0; it < 4; ++it) {
                    const int r = (tid >> 6) + (it << 3);
                    *(float4*)&ldsB[r * DT2 + c4] =
                        *(const float4*)(v + (size_t)(rr0 + r) * D + d0 + c4);
                }
            }
            __syncthreads();
#pragma unroll
            for (int k = 0; k < RK2; ++k) {
                float4 wf = *(const float4*)&ldsA[k * 64 + t0];
                float4 v0 = *(const float4*)&ldsB[k * DT2 + (tx << 3)];
                float4 v1 = *(const float4*)&ldsB[k * DT2 + (tx << 3) + 4];
                float ar[4] = {wf.x, wf.y, wf.z, wf.w};
                float br[8] = {v0.x, v0.y, v0.z, v0.w, v1.x, v1.y, v1.z, v1.w};
#pragma unroll
                for (int i = 0; i < 4; ++i)
#pragma unroll
                    for (int j = 0; j < 8; ++j)
                        acc[i][j] = fmaf(ar[i], br[j], acc[i][j]);
            }
            __syncthreads();
        }
        // epilogue: normalize by Z, accumulate cos1 pieces
#pragma unroll
        for (int i = 0; i < 4; ++i) {
            const int trow = t0 + i;
            const float invZ = 1.0f / s_Z[trow];
            float dp = 0.f, sv = 0.f, s2 = 0.f;
#pragma unroll
            for (int j = 0; j < 8; ++j) {
                const float vt = acc[i][j] * invZ;
                const float ee = ldsC[trow * SIMP + (tx << 3) + j];
                dp += vt * ee;
                sv += vt * vt;
                s2 += ee * ee;
            }
            atomicAdd(&s_dotve[trow], dp);
            atomicAdd(&s_ssvt[trow], sv);
            atomicAdd(&s_sse[trow], s2);
        }
        __syncthreads();
    }

    if (tid < 64)
        s_redA[tid] = s_dotve[tid] / (sqrtf(s_ssvt[tid]) * sqrtf(s_sse[tid]));
    __syncthreads();
    if (tid == 0) {
        float s = 0.f;
        for (int t = 0; t < 64; ++t) s += s_redA[t];
        s_scal[0] = logf(s) / G2;   // R_QD
    }

    // ---------------- Tail: e_prime (ldsC as [d][16]), cos2, R_QD2 ----------------
    for (int dt8 = 0; dt8 < 8; ++dt8) {
        const int d0 = dt8 * 128;
        {   // stage e [t][128] into ldsB
            const int trow = tid >> 3, cb = (tid & 7) << 2;
#pragma unroll
            for (int it = 0; it < 4; ++it) {
                const int c = cb + (it << 5);
                *(float4*)&ldsB[trow * 128 + c] =
                    *(const float4*)(e + (size_t)trow * D + d0 + c);
            }
        }
        __syncthreads();
        {
            const int dl = tid >> 2, mq = (tid & 3) << 2;
            float ep[4] = {0.f, 0.f, 0.f, 0.f};
            for (int t = 0; t < 64; ++t) {
                const float ev = ldsB[t * 128 + dl];
#pragma unroll
                for (int j = 0; j < 4; ++j)
                    ep[j] = fmaf(ev, s_beta[t * 16 + mq + j], ep[j]);
            }
#pragma unroll
            for (int j = 0; j < 4; ++j) {
                ldsC[(d0 + dl) * 16 + mq + j] = ep[j];
                atomicAdd(&s_ssep[mq + j], ep[j] * ep[j]);
            }
        }
        __syncthreads();
    }

    // per-region dots against e_prime column m (v rows stream from L2/L3)
    for (int r = tid; r < V; r += 512) {
        const int m = r >> 6;
        const float* __restrict__ vr = v + (size_t)r * D;
        float dot = 0.f, nsq = 0.f;
        for (int d = 0; d < D; d += 4) {
            float4 f = *(const float4*)(vr + d);
            dot += f.x * ldsC[(d + 0) * 16 + m] + f.y * ldsC[(d + 1) * 16 + m]
                 + f.z * ldsC[(d + 2) * 16 + m] + f.w * ldsC[(d + 3) * 16 + m];
            nsq += f.x * f.x + f.y * f.y + f.z * f.z + f.w * f.w;
        }
        const float c2 = dot / (sqrtf(nsq) * sqrtf(s_ssep[m]));
        atomicAdd(&s_ref[m], c2 * (1.0f / 64.0f));
    }
    __syncthreads();
    if (tid == 0) {
        float s = 0.f;
        for (int m = 0; m < 16; ++m) s += expf(s_ref[m]);
        ws[WS_S + a * 16 + b] = s_scal[0] + logf(s) / G2;
    }
}

__global__ __launch_bounds__(256)
void finalize_kernel(const float* __restrict__ ws, float* __restrict__ out)
{
    __shared__ float es[256];
    __shared__ float sbeta[1024];
    __shared__ float s_acc[256];
    __shared__ float s_out[2];
    const int tid = threadIdx.x;
    es[tid] = G3 * expf(ws[WS_S + tid]);
    __syncthreads();
    if (tid == 0) {
        float l = 0.f;
        for (int i = 0; i < 16; ++i) {
            float rs = 0.f, cs = 0.f;
            for (int j = 0; j < 16; ++j) { rs += es[i * 16 + j]; cs += es[j * 16 + i]; }
            const float num = es[i * 16 + i];
            l -= num / rs;   // loss1
            l -= num / cs;   // loss2
        }
        s_out[0] = l;
        s_out[1] = 0.f;
    }
    for (int i = 0; i < 16; ++i) {
        for (int idx = tid; idx < 1024; idx += 256)
            sbeta[idx] = ws[WS_BETA + i * 1024 + idx];
        __syncthreads();
        float part = 0.f;
        for (int idx = tid; idx < 4096; idx += 256) {
            const int t = idx >> 6, s = idx & 63;
            float bt = 0.f, ds = 0.f;
            for (int m = 0; m < 16; ++m) {
                bt += sbeta[t * 16 + m] * sbeta[s * 16 + m];
                ds += sbeta[s * 16 + m] * sbeta[s * 16 + m];
            }
            const float df = bt - ds;   // B[t][s] - B[s][s]
            part += df * df;
        }
        s_acc[tid] = part;
        __syncthreads();
        if (tid == 0) {
            float tot = 0.f;
            for (int j = 0; j < 256; ++j) tot += s_acc[j];
            s_out[1] += sqrtf(tot);
        }
        __syncthreads();
    }
    if (tid == 0) out[0] = s_out[0] + s_out[1];
}

extern "C" void kernel_launch(void* const* d_in, const int* in_sizes, int n_in,
                              void* d_out, int out_size, void* d_ws, size_t ws_size,
                              hipStream_t stream)
{
    const float* E  = (const float*)d_in[0];
    const float* Vb = (const float*)d_in[1];
    float* ws  = (float*)d_ws;
    float* out = (float*)d_out;

    const long ws_floats = (long)(ws_size / 4);
    long avail = ws_floats - WS_W;
    int fit = (avail > 0) ? (int)(avail / WPP) : 0;
    if (fit < 1) fit = 1;

    if (fit >= 256) {
        sim_pair_kernel<<<dim3(256), dim3(512), 0, stream>>>(E, Vb, ws, 0, 1);
    } else {
        for (int base = 0; base < 256; base += fit) {
            const int g = (256 - base < fit) ? (256 - base) : fit;
            sim_pair_kernel<<<dim3(g), dim3(512), 0, stream>>>(E, Vb, ws, base, 0);
        }
    }
    finalize_kernel<<<dim3(1), dim3(256), 0, stream>>>(ws, out);
}

// Round 2
// 788.231 us; speedup vs baseline: 2.1847x; 2.1847x over previous
//
#include <hip/hip_runtime.h>
#include <math.h>

namespace {
constexpr int T = 64, D = 1024, V = 1024;
constexpr float G1 = 5.0f, G2 = 5.0f, G3 = 10.0f;
// ---- old-path (fallback) ws layout ----
constexpr int RT1 = 256;
constexpr int KT  = 32;
constexpr int DT2 = 256;
constexpr int RK2 = 32;
constexpr int SIMP = 260;
constexpr int WS_S    = 0;
constexpr int WS_BETA = 256;
constexpr int WS_W    = 32768;
constexpr int WPP     = T * V;

// ---- new-path ws layout (float offsets) ----
constexpr size_t O_VH    = 0;          // v hi plane: 16M shorts = 8M floats
constexpr size_t O_VL    = 8388608;
constexpr size_t O_EH    = 16777216;   // e hi plane: 1M shorts = 512K floats
constexpr size_t O_EL    = 17301504;
constexpr size_t O_ATTN  = 17825792;   // attn fp32: 256*64*1024
constexpr size_t O_BETA  = 34603008;   // 256*1024
constexpr size_t O_EP    = 34865152;   // e_prime: 256*1024*16
constexpr size_t O_DOTVE = 39059456;   // 256*64
constexpr size_t O_NSQ   = 39075840;   // 256*64
constexpr size_t O_EN2   = 39092224;   // 16*64
constexpr size_t O_VN2   = 39093248;   // 16*1024
constexpr size_t O_EPN2  = 39109632;   // 256*16
constexpr size_t O_REF   = 39113728;   // 256*16
constexpr size_t WS_TOTAL_F = 39118080;
}

using s16x8  = __attribute__((ext_vector_type(8))) short;
using f32x16 = __attribute__((ext_vector_type(16))) float;

__device__ __forceinline__ short f2bf(float x) {
    unsigned u = __float_as_uint(x);
    unsigned r = (u + 0x7FFFu + ((u >> 16) & 1u)) >> 16;
    return (short)r;
}
__device__ __forceinline__ float bf2f(short h) {
    return __uint_as_float(((unsigned)(unsigned short)h) << 16);
}

// ============================ NEW PATH ============================

// Convert E, V to bf16 hi/lo planes; compute row norms.
__global__ __launch_bounds__(256)
void split_kernel(const float* __restrict__ E, const float* __restrict__ Vb,
                  float* __restrict__ ws)
{
    const int tid = threadIdx.x, b = blockIdx.x;
    const int sub = tid >> 5, lane32 = tid & 31;
    const float* src; short* dh; short* dl; float* nout; int row;
    if (b < 2048) {                 // V: 16384 rows, 8 per block
        row = b * 8 + sub;
        src = Vb + (size_t)row * 1024;
        dh = (short*)(ws + O_VH) + (size_t)row * 1024;
        dl = (short*)(ws + O_VL) + (size_t)row * 1024;
        nout = ws + O_VN2 + row;
    } else {                        // E: 1024 rows
        row = (b - 2048) * 8 + sub;
        src = E + (size_t)row * 1024;
        dh = (short*)(ws + O_EH) + (size_t)row * 1024;
        dl = (short*)(ws + O_EL) + (size_t)row * 1024;
        nout = ws + O_EN2 + row;
    }
    float nrm = 0.f;
#pragma unroll
    for (int i = 0; i < 8; ++i) {
        const int c = lane32 * 4 + i * 128;
        float4 f = *(const float4*)(src + c);
        short4 hs, ls;
        hs.x = f2bf(f.x); ls.x = f2bf(f.x - bf2f(hs.x));
        hs.y = f2bf(f.y); ls.y = f2bf(f.y - bf2f(hs.y));
        hs.z = f2bf(f.z); ls.z = f2bf(f.z - bf2f(hs.z));
        hs.w = f2bf(f.w); ls.w = f2bf(f.w - bf2f(hs.w));
        *(short4*)(dh + c) = hs;
        *(short4*)(dl + c) = ls;
        nrm += f.x*f.x + f.y*f.y + f.z*f.z + f.w*f.w;
    }
#pragma unroll
    for (int off = 16; off; off >>= 1) nrm += __shfl_xor(nrm, off);
    if (lane32 == 0) *nout = nrm;
}

// One block per pair p=(a,b): sim = e_b @ v_a^T (split bf16 MFMA), fused
// column softmax -> nsim, W=exp(5 nsim), Z, beta, dot(v_tilde,e); writes attn.
__global__ __launch_bounds__(512, 2)
void stageA_kernel(float* __restrict__ ws)
{
    __shared__ short sE[2][64 * 32];
    __shared__ short sV[2][1024 * 32];
    __shared__ float sZw[512], sDw[512], s_bnum[1024], s_bsum[16], s_invZ[64];

    const int tid = threadIdx.x;
    const int L = (int)(blockIdx.x >> 3) + (int)(blockIdx.x & 7) * 32;  // XCD chunking
    const int p = L, a = p >> 4, bb = p & 15;
    const int w = tid >> 6, lane = tid & 63, l31 = lane & 31, h = lane >> 5;

    const short* vhp = (const short*)(ws + O_VH) + (size_t)a * (1024 * 1024);
    const short* vlp = (const short*)(ws + O_VL) + (size_t)a * (1024 * 1024);
    const short* ehp = (const short*)(ws + O_EH) + (size_t)bb * (64 * 1024);
    const short* elp = (const short*)(ws + O_EL) + (size_t)bb * (64 * 1024);
    float* attnp = ws + O_ATTN + (size_t)p * 65536;

    f32x16 acc[2][4] = {};

    for (int kt = 0; kt < 32; ++kt) {
        const int k0 = kt << 5;
        {   // e tile: 512 16B-units, one per thread
            const int pp = tid >> 8, row = (tid >> 2) & 63, q = tid & 3;
            const short* g = pp ? elp : ehp;
            s16x8 dvec = *(const s16x8*)(g + (size_t)row * 1024 + k0 + (q << 3));
            *(s16x8*)&sE[pp][(row << 5) + ((q ^ (row & 3)) << 3)] = dvec;
        }
#pragma unroll
        for (int pp = 0; pp < 2; ++pp) {    // v tile: 4096 units/plane
            const short* g = pp ? vlp : vhp;
#pragma unroll
            for (int i = 0; i < 8; ++i) {
                const int u = tid + (i << 9);
                const int row = u >> 2, q = u & 3;
                s16x8 dvec = *(const s16x8*)(g + (size_t)row * 1024 + k0 + (q << 3));
                *(s16x8*)&sV[pp][(row << 5) + ((q ^ (row & 3)) << 3)] = dvec;
            }
        }
        __syncthreads();
#pragma unroll
        for (int kk = 0; kk < 2; ++kk) {
            const int unit = (kk << 1) + h;
            s16x8 ah[2], al[2];
#pragma unroll
            for (int rs = 0; rs < 2; ++rs) {
                const int row = (rs << 5) + l31;
                const int off = (row << 5) + ((unit ^ (row & 3)) << 3);
                ah[rs] = *(const s16x8*)&sE[0][off];
                al[rs] = *(const s16x8*)&sE[1][off];
            }
#pragma unroll
            for (int cs = 0; cs < 4; ++cs) {
                const int r = (w << 7) + (cs << 5) + l31;
                const int off = (r << 5) + ((unit ^ (r & 3)) << 3);
                const s16x8 bh = *(const s16x8*)&sV[0][off];
                const s16x8 bl = *(const s16x8*)&sV[1][off];
#pragma unroll
                for (int rs = 0; rs < 2; ++rs) {
                    acc[rs][cs] = __builtin_amdgcn_mfma_f32_32x32x16_bf16(ah[rs], bh, acc[rs][cs], 0, 0, 0);
                    acc[rs][cs] = __builtin_amdgcn_mfma_f32_32x32x16_bf16(ah[rs], bl, acc[rs][cs], 0, 0, 0);
                    acc[rs][cs] = __builtin_amdgcn_mfma_f32_32x32x16_bf16(al[rs], bh, acc[rs][cs], 0, 0, 0);
                }
            }
        }
        __syncthreads();
    }

    // ---- column (over t) softmax stats: col is lane-local ----
    float cmax[4], cinv[4];
#pragma unroll
    for (int cs = 0; cs < 4; ++cs) {
        float mx = -1e30f;
#pragma unroll
        for (int rs = 0; rs < 2; ++rs)
#pragma unroll
            for (int q = 0; q < 16; ++q) mx = fmaxf(mx, acc[rs][cs][q]);
        mx = fmaxf(mx, __shfl_xor(mx, 32));
        float sm = 0.f;
#pragma unroll
        for (int rs = 0; rs < 2; ++rs)
#pragma unroll
            for (int q = 0; q < 16; ++q) sm += __expf(acc[rs][cs][q] - mx);
        sm += __shfl_xor(sm, 32);
        cmax[cs] = mx; cinv[cs] = 1.0f / sm;
    }
    // ---- per-row: W=exp(5 nsim)=se^5, Z, dot(W,sim), bnum; acc := W ----
#pragma unroll
    for (int rs = 0; rs < 2; ++rs) {
#pragma unroll
        for (int q = 0; q < 16; ++q) {
            float zp = 0.f, dp = 0.f, bn0 = 0.f, bn1 = 0.f;
#pragma unroll
            for (int cs = 0; cs < 4; ++cs) {
                const float sim = acc[rs][cs][q];
                const float ns = __expf(sim - cmax[cs]) * cinv[cs];
                const float se = __expf(ns);
                float w5 = se * se; w5 = w5 * w5; w5 *= se;
                zp += w5; dp += w5 * sim;
                if (cs < 2) bn0 += se; else bn1 += se;
                acc[rs][cs][q] = w5;
            }
#pragma unroll
            for (int off = 16; off; off >>= 1) {
                zp  += __shfl_xor(zp, off);
                dp  += __shfl_xor(dp, off);
                bn0 += __shfl_xor(bn0, off);
                bn1 += __shfl_xor(bn1, off);
            }
            if (l31 == 0) {
                const int t = (rs << 5) + (q & 3) + ((q >> 2) << 3) + (h << 2);
                sZw[(w << 6) + t] = zp;
                sDw[(w << 6) + t] = dp;
                s_bnum[(t << 4) + (w << 1)]     = bn0;
                s_bnum[(t << 4) + (w << 1) + 1] = bn1;
            }
        }
    }
    __syncthreads();
    if (tid < 64) {
        float Z = 0.f, dv = 0.f;
#pragma unroll
        for (int ww = 0; ww < 8; ++ww) { Z += sZw[(ww << 6) + tid]; dv += sDw[(ww << 6) + tid]; }
        s_invZ[tid] = 1.0f / Z;
        ws[O_DOTVE + (size_t)p * 64 + tid] = dv / Z;
        ws[O_NSQ   + (size_t)p * 64 + tid] = 0.f;   // init for stageB atomics
    }
    if (tid >= 64 && tid < 80) ws[O_REF + (size_t)p * 16 + (tid - 64)] = 0.f;
    if (tid >= 128 && tid < 144) {
        float s = 0.f;
        for (int t = 0; t < 64; ++t) s += s_bnum[(t << 4) + (tid - 128)];
        s_bsum[tid - 128] = s;
    }
    __syncthreads();
    for (int idx = tid; idx < 1024; idx += 512)
        ws[O_BETA + (size_t)p * 1024 + idx] = s_bnum[idx] / s_bsum[idx & 15];
    // attn = W * invZ -> ws (fp32, coalesced over r)
#pragma unroll
    for (int rs = 0; rs < 2; ++rs)
#pragma unroll
        for (int q = 0; q < 16; ++q) {
            const int t = (rs << 5) + (q & 3) + ((q >> 2) << 3) + (h << 2);
            const float iz = s_invZ[t];
#pragma unroll
            for (int cs = 0; cs < 4; ++cs) {
                const int r = (w << 7) + (cs << 5) + l31;
                attnp[(size_t)t * 1024 + r] = acc[rs][cs][q] * iz;
            }
        }
}

// Per a: C2 = attn_stack(1024 x 1024) @ v_a(1024 x 1024); only row-norm^2 kept.
__global__ __launch_bounds__(256, 2)
void stageB_kernel(float* __restrict__ ws)
{
    __shared__ short sA[2][128 * 32];
    __shared__ short sB[2][128 * 32];
    const int tid = threadIdx.x;
    const int L = (int)(blockIdx.x >> 3) + (int)(blockIdx.x & 7) * 128;
    const int a = L >> 6, tile = L & 63, tm = tile >> 3, tn = tile & 7;
    const int w = tid >> 6, lane = tid & 63, l31 = lane & 31, h = lane >> 5;
    const int rw = w & 1, cw = w >> 1;
    const float* attn_a = ws + O_ATTN + (size_t)a * 1048576;  // rows t_g stride 1024
    const short* vhp = (const short*)(ws + O_VH) + (size_t)a * (1024 * 1024);
    const short* vlp = (const short*)(ws + O_VL) + (size_t)a * (1024 * 1024);
    const int dqt = tid & 31, rqt = tid >> 5;
    f32x16 acc[2][2] = {};

    for (int rk = 0; rk < 32; ++rk) {
        const int r0 = rk << 5;
        // A tile: attn[tm*128 .. +127][r0..+31] fp32 -> hi/lo bf16
#pragma unroll
        for (int i = 0; i < 4; ++i) {
            const int u = tid + (i << 8);
            const int row = u >> 3, q = u & 7;
            const float4 f = *(const float4*)(attn_a + (size_t)(tm * 128 + row) * 1024 + r0 + (q << 2));
            short4 hs, ls;
            hs.x = f2bf(f.x); ls.x = f2bf(f.x - bf2f(hs.x));
            hs.y = f2bf(f.y); ls.y = f2bf(f.y - bf2f(hs.y));
            hs.z = f2bf(f.z); ls.z = f2bf(f.z - bf2f(hs.z));
            hs.w = f2bf(f.w); ls.w = f2bf(f.w - bf2f(hs.w));
            const int off = (row << 5) + ((((q >> 1) ^ (row & 3))) << 3) + ((q & 1) << 2);
            *(short4*)&sA[0][off] = hs;
            *(short4*)&sA[1][off] = ls;
        }
        // B tile: v[r0..+31][tn*128..+127] -> transposed [d][r] via 4x4 micro-transpose
#pragma unroll
        for (int pp = 0; pp < 2; ++pp) {
            const short* g = pp ? vlp : vhp;
            short4 in0 = *(const short4*)(g + (size_t)(r0 + rqt * 4 + 0) * 1024 + tn * 128 + dqt * 4);
            short4 in1 = *(const short4*)(g + (size_t)(r0 + rqt * 4 + 1) * 1024 + tn * 128 + dqt * 4);
            short4 in2 = *(const short4*)(g + (size_t)(r0 + rqt * 4 + 2) * 1024 + tn * 128 + dqt * 4);
            short4 in3 = *(const short4*)(g + (size_t)(r0 + rqt * 4 + 3) * 1024 + tn * 128 + dqt * 4);
            short4 o0 = {in0.x, in1.x, in2.x, in3.x};
            short4 o1 = {in0.y, in1.y, in2.y, in3.y};
            short4 o2 = {in0.z, in1.z, in2.z, in3.z};
            short4 o3 = {in0.w, in1.w, in2.w, in3.w};
            {   const int d = dqt * 4 + 0;
                *(short4*)&sB[pp][(d << 5) + (((rqt >> 1) ^ ((d >> 2) & 3)) << 3) + ((rqt & 1) << 2)] = o0; }
            {   const int d = dqt * 4 + 1;
                *(short4*)&sB[pp][(d << 5) + (((rqt >> 1) ^ ((d >> 2) & 3)) << 3) + ((rqt & 1) << 2)] = o1; }
            {   const int d = dqt * 4 + 2;
                *(short4*)&sB[pp][(d << 5) + (((rqt >> 1) ^ ((d >> 2) & 3)) << 3) + ((rqt & 1) << 2)] = o2; }
            {   const int d = dqt * 4 + 3;
                *(short4*)&sB[pp][(d << 5) + (((rqt >> 1) ^ ((d >> 2) & 3)) << 3) + ((rqt & 1) << 2)] = o3; }
        }
        __syncthreads();
#pragma unroll
        for (int kk = 0; kk < 2; ++kk) {
            const int unit = (kk << 1) + h;
            s16x8 ah[2], al[2];
#pragma unroll
            for (int rs = 0; rs < 2; ++rs) {
                const int row = rw * 64 + rs * 32 + l31;
                const int off = (row << 5) + ((unit ^ (row & 3)) << 3);
                ah[rs] = *(const s16x8*)&sA[0][off];
                al[rs] = *(const s16x8*)&sA[1][off];
            }
#pragma unroll
            for (int cs = 0; cs < 2; ++cs) {
                const int d = cw * 64 + cs * 32 + l31;
                const int off = (d << 5) + ((unit ^ ((d >> 2) & 3)) << 3);
                const s16x8 bh = *(const s16x8*)&sB[0][off];
                const s16x8 bl = *(const s16x8*)&sB[1][off];
#pragma unroll
                for (int rs = 0; rs < 2; ++rs) {
                    acc[rs][cs] = __builtin_amdgcn_mfma_f32_32x32x16_bf16(ah[rs], bh, acc[rs][cs], 0, 0, 0);
                    acc[rs][cs] = __builtin_amdgcn_mfma_f32_32x32x16_bf16(ah[rs], bl, acc[rs][cs], 0, 0, 0);
                    acc[rs][cs] = __builtin_amdgcn_mfma_f32_32x32x16_bf16(al[rs], bh, acc[rs][cs], 0, 0, 0);
                }
            }
        }
        __syncthreads();
    }
    // norm^2(v_tilde row) partials -> global atomics
#pragma unroll
    for (int rs = 0; rs < 2; ++rs) {
#pragma unroll
        for (int q = 0; q < 16; ++q) {
            float x = acc[rs][0][q] * acc[rs][0][q] + acc[rs][1][q] * acc[rs][1][q];
#pragma unroll
            for (int off = 16; off; off >>= 1) x += __shfl_xor(x, off);
            if (l31 == 0) {
                const int t_local = rw * 64 + rs * 32 + (q & 3) + ((q >> 2) << 3) + (h << 2);
                atomicAdd(&ws[O_NSQ + (size_t)a * 1024 + tm * 128 + t_local], x);
            }
        }
    }
}

// Per pair: e_prime[d][m] = sum_t e[t][d]*beta[t][m]; epn2[m].
__global__ __launch_bounds__(256)
void tail1_kernel(const float* __restrict__ E, float* __restrict__ ws)
{
    __shared__ float s_beta[1024];
    __shared__ float e_lds[64 * 128];
    __shared__ float s_eps[16];
    const int tid = threadIdx.x, p = blockIdx.x, bb = p & 15;
#pragma unroll
    for (int i = 0; i < 4; ++i)
        s_beta[tid + (i << 8)] = ws[O_BETA + (size_t)p * 1024 + tid + (i << 8)];
    if (tid < 16) s_eps[tid] = 0.f;
    const int dl = tid >> 1, m0 = (tid & 1) * 8;
    float s2[8] = {0.f,0.f,0.f,0.f,0.f,0.f,0.f,0.f};
    for (int ch = 0; ch < 8; ++ch) {
        const int d0 = ch << 7;
        __syncthreads();
#pragma unroll
        for (int i = 0; i < 8; ++i) {
            const int u = tid + (i << 8);
            const int row = u >> 5, q = u & 31;
            *(float4*)&e_lds[row * 128 + q * 4] =
                *(const float4*)(E + (size_t)(bb * 64 + row) * 1024 + d0 + q * 4);
        }
        __syncthreads();
        float s[8] = {0.f,0.f,0.f,0.f,0.f,0.f,0.f,0.f};
        for (int t = 0; t < 64; ++t) {
            const float ev = e_lds[t * 128 + dl];
#pragma unroll
            for (int j = 0; j < 8; ++j) s[j] = fmaf(ev, s_beta[t * 16 + m0 + j], s[j]);
        }
        float4 lo = {s[0], s[1], s[2], s[3]}, hi = {s[4], s[5], s[6], s[7]};
        float* epr = ws + O_EP + (size_t)p * 16384 + (size_t)(d0 + dl) * 16 + m0;
        *(float4*)epr = lo; *(float4*)(epr + 4) = hi;
#pragma unroll
        for (int j = 0; j < 8; ++j) s2[j] += s[j] * s[j];
    }
#pragma unroll
    for (int j = 0; j < 8; ++j) atomicAdd(&s_eps[m0 + j], s2[j]);
    __syncthreads();
    if (tid < 16) ws[O_EPN2 + (size_t)p * 16 + tid] = s_eps[tid];
}

// Per (a, m): ref[pair][m] += mean_j cos2 over the 64 regions of block m.
__global__ __launch_bounds__(256)
void tail2_kernel(const float* __restrict__ Vb, float* __restrict__ ws)
{
    __shared__ float lds_ep[16 * 1024];
    const int tid = threadIdx.x;
    const int L = (int)(blockIdx.x >> 3) + (int)(blockIdx.x & 7) * 32;
    const int a = L >> 4, m = L & 15;
    const int w = tid >> 6, lane = tid & 63;
    for (int idx = tid; idx < 16384; idx += 256) {
        const int bbi = idx >> 10, d = idx & 1023;
        lds_ep[idx] = ws[O_EP + (size_t)(a * 16 + bbi) * 16384 + (size_t)d * 16 + m];
    }
    __syncthreads();
    for (int i = 0; i < 16; ++i) {
        const int r = m * 64 + w * 16 + i;
        const float* vr = Vb + (size_t)(a * 1024 + r) * 1024;
        float vv[16];
#pragma unroll
        for (int k = 0; k < 16; ++k) vv[k] = vr[lane + (k << 6)];
        const float vn = ws[O_VN2 + a * 1024 + r];
#pragma unroll
        for (int bbi = 0; bbi < 16; ++bbi) {
            float dot = 0.f;
#pragma unroll
            for (int k = 0; k < 16; ++k) dot = fmaf(vv[k], lds_ep[bbi * 1024 + lane + (k << 6)], dot);
#pragma unroll
            for (int off = 32; off; off >>= 1) dot += __shfl_xor(dot, off);
            if (lane == 0) {
                const float ep2 = ws[O_EPN2 + (size_t)(a * 16 + bbi) * 16 + m];
                const float c2 = dot / (sqrtf(vn) * sqrtf(ep2));
                atomicAdd(&ws[O_REF + (size_t)(a * 16 + bbi) * 16 + m], c2 * (1.0f / 64.0f));
            }
        }
    }
}

__global__ __launch_bounds__(256)
void finalize2_kernel(const float* __restrict__ ws, float* __restrict__ out)
{
    __shared__ float s_es[256];
    __shared__ float sbeta[1024];
    __shared__ float s_acc[256];
    __shared__ float s_out[2];
    const int tid = threadIdx.x;
    {   // S and exp_S per pair
        const int p = tid, bb = p & 15;
        float s1 = 0.f;
        for (int t = 0; t < 64; ++t) {
            const float dv = ws[O_DOTVE + (size_t)p * 64 + t];
            const float nq = ws[O_NSQ + (size_t)p * 64 + t];
            const float en = ws[O_EN2 + bb * 64 + t];
            s1 += dv / (sqrtf(nq) * sqrtf(en));
        }
        float s2 = 0.f;
        for (int mm = 0; mm < 16; ++mm) s2 += __expf(ws[O_REF + (size_t)p * 16 + mm]);
        const float S = logf(s1) / G2 + logf(s2) / G2;
        s_es[p] = G3 * __expf(S);
    }
    __syncthreads();
    if (tid == 0) {
        float l = 0.f;
        for (int i = 0; i < 16; ++i) {
            float rs = 0.f, cs = 0.f;
            for (int j = 0; j < 16; ++j) { rs += s_es[i * 16 + j]; cs += s_es[j * 16 + i]; }
            const float num = s_es[i * 16 + i];
            l -= num / rs;
            l -= num / cs;
        }
        s_out[0] = l; s_out[1] = 0.f;
    }
    for (int i = 0; i < 16; ++i) {
        for (int idx = tid; idx < 1024; idx += 256)
            sbeta[idx] = ws[O_BETA + (size_t)(i * 17) * 1024 + idx];
        __syncthreads();
        float part = 0.f;
        for (int idx = tid; idx < 4096; idx += 256) {
            const int t = idx >> 6, s = idx & 63;
            float bt = 0.f, ds = 0.f;
            for (int mm = 0; mm < 16; ++mm) {
                bt += sbeta[t * 16 + mm] * sbeta[s * 16 + mm];
                ds += sbeta[s * 16 + mm] * sbeta[s * 16 + mm];
            }
            const float df = bt - ds;
            part += df * df;
        }
        s_acc[tid] = part;
        __syncthreads();
        if (tid == 0) {
            float tot = 0.f;
            for (int j = 0; j < 256; ++j) tot += s_acc[j];
            s_out[1] += sqrtf(tot);
        }
        __syncthreads();
    }
    if (tid == 0) out[0] = s_out[0] + s_out[1];
}

// ============================ OLD PATH (fallback, round-1 verified) ============================

__global__ __launch_bounds__(512)
void sim_pair_kernel(const float* __restrict__ E, const float* __restrict__ Vb,
                     float* __restrict__ ws, int pair_base, int swizzle)
{
    __shared__ float ldsA[KT * 64];
    __shared__ float ldsB[KT * RT1];
    __shared__ float ldsC[64 * SIMP];
    __shared__ float s_Z[64];
    __shared__ float s_bnum[64 * 16];
    __shared__ float s_bsum[16];
    __shared__ float s_beta[64 * 16];
    __shared__ float s_redA[512];
    __shared__ float s_redB[512];
    __shared__ float s_dotve[64];
    __shared__ float s_ssvt[64];
    __shared__ float s_sse[64];
    __shared__ float s_ssep[16];
    __shared__ float s_ref[16];
    __shared__ float s_scal[2];

    const int tid = threadIdx.x;
    int p;
    if (swizzle) {
        int i = blockIdx.x;
        int xcd = i & 7, slot = i >> 3;
        int aa = xcd + 8 * (slot & 1);
        int bb = slot >> 1;
        p = aa * 16 + bb;
    } else {
        p = pair_base + blockIdx.x;
    }
    const int a = p >> 4, b = p & 15;
    const float* __restrict__ e = E + (size_t)b * T * D;
    const float* __restrict__ v = Vb + (size_t)a * V * D;
    float* __restrict__ Wg = ws + WS_W + (size_t)blockIdx.x * WPP;

    const int ty = tid >> 5;
    const int tx = tid & 31;
    const int t0 = ty << 2;

    for (int i = tid; i < 64; i += 512) { s_Z[i] = 0.f; s_dotve[i] = 0.f; s_ssvt[i] = 0.f; s_sse[i] = 0.f; }
    if (tid < 16) { s_ssep[tid] = 0.f; s_ref[tid] = 0.f; }
    __syncthreads();

    for (int rt = 0; rt < V / RT1; ++rt) {
        const int r0 = rt * RT1;
        float acc[4][8];
#pragma unroll
        for (int i = 0; i < 4; ++i)
#pragma unroll
            for (int j = 0; j < 8; ++j) acc[i][j] = 0.f;

        for (int kt = 0; kt < D / KT; ++kt) {
            const int k0 = kt * KT;
            {
                const int trow = tid >> 3, k4 = (tid & 7) << 2;
                float4 f = *(const float4*)(e + (size_t)trow * D + k0 + k4);
                ldsA[(k4 + 0) * 64 + trow] = f.x;
                ldsA[(k4 + 1) * 64 + trow] = f.y;
                ldsA[(k4 + 2) * 64 + trow] = f.z;
                ldsA[(k4 + 3) * 64 + trow] = f.w;
            }
            {
                const int k4 = (tid & 7) << 2;
#pragma unroll
                for (int it = 0; it < 4; ++it) {
                    const int rr = (tid >> 3) + (it << 6);
                    float4 f = *(const float4*)(v + (size_t)(r0 + rr) * D + k0 + k4);
                    ldsB[(k4 + 0) * RT1 + rr] = f.x;
                    ldsB[(k4 + 1) * RT1 + rr] = f.y;
                    ldsB[(k4 + 2) * RT1 + rr] = f.z;
                    ldsB[(k4 + 3) * RT1 + rr] = f.w;
                }
            }
            __syncthreads();
#pragma unroll
            for (int k = 0; k < KT; ++k) {
                float4 ef = *(const float4*)&ldsA[k * 64 + t0];
                float4 v0 = *(const float4*)&ldsB[k * RT1 + (tx << 3)];
                float4 v1 = *(const float4*)&ldsB[k * RT1 + (tx << 3) + 4];
                float ar[4] = {ef.x, ef.y, ef.z, ef.w};
                float br[8] = {v0.x, v0.y, v0.z, v0.w, v1.x, v1.y, v1.z, v1.w};
#pragma unroll
                for (int i = 0; i < 4; ++i)
#pragma unroll
                    for (int j = 0; j < 8; ++j)
                        acc[i][j] = fmaf(ar[i], br[j], acc[i][j]);
            }
            __syncthreads();
        }
#pragma unroll
        for (int i = 0; i < 4; ++i)
#pragma unroll
            for (int j = 0; j < 8; ++j)
                ldsC[(t0 + i) * SIMP + (tx << 3) + j] = acc[i][j];
        __syncthreads();

        {
            const int col = tid & 255, q = tid >> 8;
            float mx = -1e30f;
            for (int t = q * 32; t < q * 32 + 32; ++t)
                mx = fmaxf(mx, ldsC[t * SIMP + col]);
            s_redA[q * 256 + col] = mx;
            __syncthreads();
            const float cm = fmaxf(s_redA[col], s_redA[256 + col]);
            float sm = 0.f;
            for (int t = q * 32; t < q * 32 + 32; ++t) {
                float ex = expf(ldsC[t * SIMP + col] - cm);
                ldsC[t * SIMP + col] = ex;
                sm += ex;
            }
            s_redB[q * 256 + col] = sm;
            __syncthreads();
            const float cs = s_redB[col] + s_redB[256 + col];
            for (int t = q * 32; t < q * 32 + 32; ++t)
                ldsC[t * SIMP + col] = ldsC[t * SIMP + col] / cs;
        }
        __syncthreads();

        {
            const int trow = tid >> 3, cq = tid & 7;
            float zp = 0.f, sp = 0.f;
            for (int c = cq * 32; c < cq * 32 + 32; ++c) {
                const float ns = ldsC[trow * SIMP + c];
                const float se = expf(ns);
                float w = se * se; w = w * w; w = w * se;
                ldsC[trow * SIMP + c] = w;
                zp += w; sp += se;
            }
            s_redA[cq * 64 + trow] = zp;
            s_redB[cq * 64 + trow] = sp;
        }
        __syncthreads();
        if (tid < 64) {
            float z = 0.f;
            for (int cq = 0; cq < 8; ++cq) z += s_redA[cq * 64 + tid];
            s_Z[tid] += z;
        }
        if (tid < 256) {
            const int trow = tid & 63, ml = tid >> 6;
            s_bnum[trow * 16 + rt * 4 + ml] =
                s_redB[(2 * ml) * 64 + trow] + s_redB[(2 * ml + 1) * 64 + trow];
        }
        __syncthreads();
        for (int i = 0; i < 32; ++i) {
            const int idx = tid + 512 * i;
            const int trow = idx & 63, c = idx >> 6;
            Wg[(size_t)(r0 + c) * 64 + trow] = ldsC[trow * SIMP + c];
        }
        __syncthreads();
    }

    if (tid < 16) {
        float s = 0.f;
        for (int t = 0; t < 64; ++t) s += s_bnum[t * 16 + tid];
        s_bsum[tid] = s;
    }
    __syncthreads();
    for (int idx = tid; idx < 1024; idx += 512)
        s_beta[idx] = s_bnum[idx] / s_bsum[idx & 15];
    __syncthreads();
    if (a == b) {
        for (int idx = tid; idx < 1024; idx += 512)
            ws[WS_BETA + a * 1024 + idx] = s_beta[idx];
    }

    for (int dt = 0; dt < D / DT2; ++dt) {
        const int d0 = dt * DT2;
        {
            const int trow = tid >> 3, cb = (tid & 7) << 2;
#pragma unroll
            for (int it = 0; it < 8; ++it) {
                const int c = cb + (it << 5);
                *(float4*)&ldsC[trow * SIMP + c] =
                    *(const float4*)(e + (size_t)trow * D + d0 + c);
            }
        }
        float acc[4][8];
#pragma unroll
        for (int i = 0; i < 4; ++i)
#pragma unroll
            for (int j = 0; j < 8; ++j) acc[i][j] = 0.f;

        for (int rk = 0; rk < V / RK2; ++rk) {
            const int rr0 = rk * RK2;
            {
                const int r = tid >> 4, t4 = (tid & 15) << 2;
                *(float4*)&ldsA[r * 64 + t4] =
                    *(const float4*)(Wg + (size_t)(rr0 + r) * 64 + t4);
            }
            {
                const int c4 = (tid & 63) << 2;
#pragma unroll
                for (int it = 0; it < 4; ++it) {
                    const int r = (tid >> 6) + (it << 3);
                    *(float4*)&ldsB[r * DT2 + c4] =
                        *(const float4*)(v + (size_t)(rr0 + r) * D + d0 + c4);
                }
            }
            __syncthreads();
#pragma unroll
            for (int k = 0; k < RK2; ++k) {
                float4 wf = *(const float4*)&ldsA[k * 64 + t0];
                float4 v0 = *(const float4*)&ldsB[k * DT2 + (tx << 3)];
                float4 v1 = *(const float4*)&ldsB[k * DT2 + (tx << 3) + 4];
                float ar[4] = {wf.x, wf.y, wf.z, wf.w};
                float br[8] = {v0.x, v0.y, v0.z, v0.w, v1.x, v1.y, v1.z, v1.w};
#pragma unroll
                for (int i = 0; i < 4; ++i)
#pragma unroll
                    for (int j = 0; j < 8; ++j)
                        acc[i][j] = fmaf(ar[i], br[j], acc[i][j]);
            }
            __syncthreads();
        }
#pragma unroll
        for (int i = 0; i < 4; ++i) {
            const int trow = t0 + i;
            const float invZ = 1.0f / s_Z[trow];
            float dp = 0.f, sv = 0.f, s2 = 0.f;
#pragma unroll
            for (int j = 0; j < 8; ++j) {
                const float vt = acc[i][j] * invZ;
                const float ee = ldsC[trow * SIMP + (tx << 3) + j];
                dp += vt * ee;
                sv += vt * vt;
                s2 += ee * ee;
            }
            atomicAdd(&s_dotve[trow], dp);
            atomicAdd(&s_ssvt[trow], sv);
            atomicAdd(&s_sse[trow], s2);
        }
        __syncthreads();
    }

    if (tid < 64)
        s_redA[tid] = s_dotve[tid] / (sqrtf(s_ssvt[tid]) * sqrtf(s_sse[tid]));
    __syncthreads();
    if (tid == 0) {
        float s = 0.f;
        for (int t = 0; t < 64; ++t) s += s_redA[t];
        s_scal[0] = logf(s) / G2;
    }

    for (int dt8 = 0; dt8 < 8; ++dt8) {
        const int d0 = dt8 * 128;
        {
            const int trow = tid >> 3, cb = (tid & 7) << 2;
#pragma unroll
            for (int it = 0; it < 4; ++it) {
                const int c = cb + (it << 5);
                *(float4*)&ldsB[trow * 128 + c] =
                    *(const float4*)(e + (size_t)trow * D + d0 + c);
            }
        }
        __syncthreads();
        {
            const int dl = tid >> 2, mq = (tid & 3) << 2;
            float ep[4] = {0.f, 0.f, 0.f, 0.f};
            for (int t = 0; t < 64; ++t) {
                const float ev = ldsB[t * 128 + dl];
#pragma unroll
                for (int j = 0; j < 4; ++j)
                    ep[j] = fmaf(ev, s_beta[t * 16 + mq + j], ep[j]);
            }
#pragma unroll
            for (int j = 0; j < 4; ++j) {
                ldsC[(d0 + dl) * 16 + mq + j] = ep[j];
                atomicAdd(&s_ssep[mq + j], ep[j] * ep[j]);
            }
        }
        __syncthreads();
    }

    for (int r = tid; r < V; r += 512) {
        const int m = r >> 6;
        const float* __restrict__ vr = v + (size_t)r * D;
        float dot = 0.f, nsq = 0.f;
        for (int d = 0; d < D; d += 4) {
            float4 f = *(const float4*)(vr + d);
            dot += f.x * ldsC[(d + 0) * 16 + m] + f.y * ldsC[(d + 1) * 16 + m]
                 + f.z * ldsC[(d + 2) * 16 + m] + f.w * ldsC[(d + 3) * 16 + m];
            nsq += f.x * f.x + f.y * f.y + f.z * f.z + f.w * f.w;
        }
        const float c2 = dot / (sqrtf(nsq) * sqrtf(s_ssep[m]));
        atomicAdd(&s_ref[m], c2 * (1.0f / 64.0f));
    }
    __syncthreads();
    if (tid == 0) {
        float s = 0.f;
        for (int m = 0; m < 16; ++m) s += expf(s_ref[m]);
        ws[WS_S + a * 16 + b] = s_scal[0] + logf(s) / G2;
    }
}

__global__ __launch_bounds__(256)
void finalize_kernel(const float* __restrict__ ws, float* __restrict__ out)
{
    __shared__ float es[256];
    __shared__ float sbeta[1024];
    __shared__ float s_acc[256];
    __shared__ float s_out[2];
    const int tid = threadIdx.x;
    es[tid] = G3 * expf(ws[WS_S + tid]);
    __syncthreads();
    if (tid == 0) {
        float l = 0.f;
        for (int i = 0; i < 16; ++i) {
            float rs = 0.f, cs = 0.f;
            for (int j = 0; j < 16; ++j) { rs += es[i * 16 + j]; cs += es[j * 16 + i]; }
            const float num = es[i * 16 + i];
            l -= num / rs;
            l -= num / cs;
        }
        s_out[0] = l;
        s_out[1] = 0.f;
    }
    for (int i = 0; i < 16; ++i) {
        for (int idx = tid; idx < 1024; idx += 256)
            sbeta[idx] = ws[WS_BETA + i * 1024 + idx];
        __syncthreads();
        float part = 0.f;
        for (int idx = tid; idx < 4096; idx += 256) {
            const int t = idx >> 6, s = idx & 63;
            float bt = 0.f, ds = 0.f;
            for (int m = 0; m < 16; ++m) {
                bt += sbeta[t * 16 + m] * sbeta[s * 16 + m];
                ds += sbeta[s * 16 + m] * sbeta[s * 16 + m];
            }
            const float df = bt - ds;
            part += df * df;
        }
        s_acc[tid] = part;
        __syncthreads();
        if (tid == 0) {
            float tot = 0.f;
            for (int j = 0; j < 256; ++j) tot += s_acc[j];
            s_out[1] += sqrtf(tot);
        }
        __syncthreads();
    }
    if (tid == 0) out[0] = s_out[0] + s_out[1];
}

// ============================ launch ============================

extern "C" void kernel_launch(void* const* d_in, const int* in_sizes, int n_in,
                              void* d_out, int out_size, void* d_ws, size_t ws_size,
                              hipStream_t stream)
{
    const float* E  = (const float*)d_in[0];
    const float* Vb = (const float*)d_in[1];
    float* ws  = (float*)d_ws;
    float* out = (float*)d_out;

    if (ws_size >= (size_t)WS_TOTAL_F * 4) {
        split_kernel<<<dim3(2176), dim3(256), 0, stream>>>(E, Vb, ws);
        stageA_kernel<<<dim3(256), dim3(512), 0, stream>>>(ws);
        stageB_kernel<<<dim3(1024), dim3(256), 0, stream>>>(ws);
        tail1_kernel<<<dim3(256), dim3(256), 0, stream>>>(E, ws);
        tail2_kernel<<<dim3(256), dim3(256), 0, stream>>>(Vb, ws);
        finalize2_kernel<<<dim3(1), dim3(256), 0, stream>>>(ws, out);
        return;
    }

    // fallback: round-1 verified path
    const long ws_floats = (long)(ws_size / 4);
    long avail = ws_floats - WS_W;
    int fit = (avail > 0) ? (int)(avail / WPP) : 0;
    if (fit < 1) fit = 1;

    if (fit >= 256) {
        sim_pair_kernel<<<dim3(256), dim3(512), 0, stream>>>(E, Vb, ws, 0, 1);
    } else {
        for (int base = 0; base < 256; base += fit) {
            const int g = (256 - base < fit) ? (256 - base) : fit;
            sim_pair_kernel<<<dim3(g), dim3(512), 0, stream>>>(E, Vb, ws, base, 0);
        }
    }
    finalize_kernel<<<dim3(1), dim3(256), 0, stream>>>(ws, out);
}

// Round 6
// 746.890 us; speedup vs baseline: 2.3057x; 1.0554x over previous
//
#include <hip/hip_runtime.h>
#include <math.h>

namespace {
constexpr float G1 = 5.0f, G2 = 5.0f, G3 = 10.0f;

// ---------- round-2 (fallback) ws layout ----------
constexpr size_t O_VH    = 0;
constexpr size_t O_VL    = 8388608;
constexpr size_t O_EH    = 16777216;
constexpr size_t O_EL    = 17301504;
constexpr size_t O_ATTN  = 17825792;
constexpr size_t O_BETA  = 34603008;
constexpr size_t O_EP    = 34865152;
constexpr size_t O_DOTVE = 39059456;
constexpr size_t O_NSQ   = 39075840;
constexpr size_t O_EN2   = 39092224;
constexpr size_t O_VN2   = 39093248;
constexpr size_t O_EPN2  = 39109632;
constexpr size_t O_REF   = 39113728;
constexpr size_t WS_TOTAL_F = 39118080;

// ---------- v3 ws layout (floats) ----------
constexpr size_t P3_VFH  = 0;         // V row-frag hi: [a][kt32][u4][r1024]x8sh
constexpr size_t P3_VFL  = 8388608;
constexpr size_t P3_VTFH = 16777216;  // V^T frag hi: [a][ktr32][u4][d1024]x8sh
constexpr size_t P3_VTFL = 25165824;
constexpr size_t P3_EFH  = 33554432;  // E frag hi: [b][kt32][u4][t64]x8sh
constexpr size_t P3_EFL  = 34078720;
constexpr size_t P3_WH   = 34603008;  // W hi: [p][t64][r1024] shorts
constexpr size_t P3_WL   = 42991616;
constexpr size_t P3_ACC  = 51380224;  // zeroed region start
constexpr size_t P3_BNUM = P3_ACC;                // 262144
constexpr size_t P3_DP   = P3_ACC + 262144;       // 16384
constexpr size_t P3_NSQ  = P3_DP + 16384;         // 16384
constexpr size_t P3_REF  = P3_NSQ + 16384;        // 4096
constexpr size_t P3_VN2  = P3_REF + 4096;         // 16384
constexpr size_t P3_EN2  = P3_VN2 + 16384;        // 1024
constexpr size_t P3_ACCN = 316416;                // floats memset to 0
constexpr size_t P3_BETA = P3_ACC + P3_ACCN;      // 262144
constexpr size_t P3_EP   = P3_BETA + 262144;      // 4194304
constexpr size_t P3_EPN2 = P3_EP + 4194304;       // 4096
constexpr size_t P3_TOTAL = P3_EPN2 + 4096;       // 56,157,184 floats
}

using s16x8  = __attribute__((ext_vector_type(8))) short;
using f32x16 = __attribute__((ext_vector_type(16))) float;

__device__ __forceinline__ short f2bf(float x) {
    unsigned u = __float_as_uint(x);
    unsigned r = (u + 0x7FFFu + ((u >> 16) & 1u)) >> 16;
    return (short)r;
}
__device__ __forceinline__ float bf2f(short h) {
    return __uint_as_float(((unsigned)(unsigned short)h) << 16);
}
__device__ __forceinline__ void gll16(const void* g, void* l) {
    __builtin_amdgcn_global_load_lds(
        (const __attribute__((address_space(1))) void*)g,
        (__attribute__((address_space(3))) void*)l, 16, 0, 0);
}

// ============================ V3 PATH ============================

// Pack V into fragment-major hi/lo planes (row-frags VF and transposed VTF),
// plus per-row norms. grid: a(16) x rb(16) x db(16); 256 threads.
__global__ __launch_bounds__(256)
void pack_v3(const float* __restrict__ Vb, float* __restrict__ ws)
{
    __shared__ float tile[64][68];
    const int tid = threadIdx.x;
    const int a = blockIdx.x >> 8, rb = (blockIdx.x >> 4) & 15, db = blockIdx.x & 15;
    const float* src = Vb + (size_t)(a * 1024 + rb * 64) * 1024 + db * 64;
    {
        const int row = tid >> 2, cq = (tid & 3) << 4;
#pragma unroll
        for (int i = 0; i < 4; ++i) {
            float4 f = *(const float4*)(src + (size_t)row * 1024 + cq + i * 4);
            tile[row][cq + i * 4 + 0] = f.x;
            tile[row][cq + i * 4 + 1] = f.y;
            tile[row][cq + i * 4 + 2] = f.z;
            tile[row][cq + i * 4 + 3] = f.w;
        }
    }
    __syncthreads();
    if (tid < 64) {
        float s = 0.f;
        for (int c = 0; c < 64; ++c) { const float x = tile[tid][c]; s += x * x; }
        atomicAdd(&ws[P3_VN2 + (size_t)a * 1024 + rb * 64 + tid], s);
    }
    short* vfh = (short*)(ws + P3_VFH) + (size_t)a * 1048576;
    short* vfl = (short*)(ws + P3_VFL) + (size_t)a * 1048576;
    short* vth = (short*)(ws + P3_VTFH) + (size_t)a * 1048576;
    short* vtl = (short*)(ws + P3_VTFL) + (size_t)a * 1048576;
#pragma unroll
    for (int jj = 0; jj < 2; ++jj) {              // row-frags
        const int j = tid + (jj << 8);
        const int r = j & 63, ku = j >> 6;
        const int ktl = ku >> 2, u = ku & 3, dl = ktl * 32 + u * 8;
        s16x8 hv, lv;
#pragma unroll
        for (int i = 0; i < 8; ++i) {
            const float x = tile[r][dl + i];
            const short hs = f2bf(x);
            hv[i] = hs; lv[i] = f2bf(x - bf2f(hs));
        }
        const size_t off = ((size_t)((db * 2 + ktl) * 4 + u) * 1024 + rb * 64 + r) * 8;
        *(s16x8*)(vfh + off) = hv;
        *(s16x8*)(vfl + off) = lv;
    }
#pragma unroll
    for (int jj = 0; jj < 2; ++jj) {              // transposed frags
        const int j = tid + (jj << 8);
        const int d = j & 63, ku = j >> 6;
        const int ktl = ku >> 2, ur = ku & 3, rl = ktl * 32 + ur * 8;
        s16x8 hv, lv;
#pragma unroll
        for (int i = 0; i < 8; ++i) {
            const float x = tile[rl + i][d];
            const short hs = f2bf(x);
            hv[i] = hs; lv[i] = f2bf(x - bf2f(hs));
        }
        const size_t off = ((size_t)((rb * 2 + ktl) * 4 + ur) * 1024 + db * 64 + d) * 8;
        *(s16x8*)(vth + off) = hv;
        *(s16x8*)(vtl + off) = lv;
    }
}

// Pack E into EF fragment planes + row norms. grid 16 (b), 512 threads.
__global__ __launch_bounds__(512)
void pack_e3(const float* __restrict__ E, float* __restrict__ ws)
{
    const int tid = threadIdx.x, b = blockIdx.x;
    short* efh = (short*)(ws + P3_EFH);
    short* efl = (short*)(ws + P3_EFL);
#pragma unroll
    for (int jj = 0; jj < 16; ++jj) {
        const int j = tid + (jj << 9);
        const int t = j & 63, ku = j >> 6;          // ku 0..127
        const int kt = ku >> 2, u = ku & 3;
        const float* ep = E + (size_t)b * 65536 + (size_t)t * 1024 + kt * 32 + u * 8;
        float4 f0 = *(const float4*)ep;
        float4 f1 = *(const float4*)(ep + 4);
        float vals[8] = {f0.x, f0.y, f0.z, f0.w, f1.x, f1.y, f1.z, f1.w};
        s16x8 hv, lv;
#pragma unroll
        for (int i = 0; i < 8; ++i) {
            const short hs = f2bf(vals[i]);
            hv[i] = hs; lv[i] = f2bf(vals[i] - bf2f(hs));
        }
        const size_t off = ((size_t)((b * 32 + kt) * 4 + u) * 64 + t) * 8;
        *(s16x8*)(efh + off) = hv;
        *(s16x8*)(efl + off) = lv;
    }
    {   // EN2
        const int t = tid >> 3, g = tid & 7;
        const float* er = E + (size_t)b * 65536 + (size_t)t * 1024 + g * 128;
        float s = 0.f;
#pragma unroll
        for (int i = 0; i < 32; ++i) {
            float4 f = *(const float4*)(er + i * 4);
            s += f.x * f.x + f.y * f.y + f.z * f.z + f.w * f.w;
        }
        s += __shfl_xor(s, 1); s += __shfl_xor(s, 2); s += __shfl_xor(s, 4);
        if (g == 0) atomicAdd(&ws[P3_EN2 + (size_t)b * 64 + t], s);
    }
}

// sim GEMM + fused column softmax -> W (split bf16), DP, BNUM.
// grid 512 = (a,bb,rh); 512 threads; B-frags direct from VF; A via LDS+gll.
__global__ __launch_bounds__(512, 4)
void stageA3(float* __restrict__ ws)
{
    __shared__ short sE[2 * 4096];
    const int tid = threadIdx.x;
    const int xcd = blockIdx.x & 7, slot = blockIdx.x >> 3;
    const int a = (xcd << 1) | (slot >> 5);
    const int bb = (slot >> 1) & 15;
    const int rh = slot & 1;
    const int p = a * 16 + bb;
    const int w = tid >> 6, l31 = tid & 31, h = (tid >> 5) & 1;

    const short* __restrict__ vfh = (const short*)(ws + P3_VFH) + (size_t)a * 1048576;
    const short* __restrict__ vfl = (const short*)(ws + P3_VFL) + (size_t)a * 1048576;
    const short* __restrict__ efh = (const short*)(ws + P3_EFH) + (size_t)bb * 65536;
    const short* __restrict__ efl = (const short*)(ws + P3_EFL) + (size_t)bb * 65536;
    short* __restrict__ Wh = (short*)(ws + P3_WH) + ((size_t)p << 16);
    short* __restrict__ Wl = (short*)(ws + P3_WL) + ((size_t)p << 16);

    const int s_pl = tid >> 8, rest = tid & 255;
    const short* sg = (s_pl ? efl : efh) + (size_t)rest * 8;  // + kt*2048
    const int rbase = (rh << 9) + (w << 6) + l31;

    f32x16 acc[2][2] = {};
    gll16(sg, &sE[tid * 8]);
    __syncthreads();

    for (int kt = 0; kt < 32; ++kt) {
        const int cur = kt & 1;
        const short* vkh = vfh + (size_t)kt * 32768;
        const short* vkl = vfl + (size_t)kt * 32768;
#pragma unroll
        for (int kk = 0; kk < 2; ++kk) {
            const int u = (kk << 1) + h;
            const int ao = cur * 4096 + u * 512 + l31 * 8;
            const s16x8 ah0 = *(const s16x8*)&sE[ao];
            const s16x8 ah1 = *(const s16x8*)&sE[ao + 256];
            const s16x8 al0 = *(const s16x8*)&sE[ao + 2048];
            const s16x8 al1 = *(const s16x8*)&sE[ao + 2304];
            const size_t bo = (size_t)u * 8192 + (size_t)rbase * 8;
            const s16x8 bh0 = *(const s16x8*)(vkh + bo);
            const s16x8 bh1 = *(const s16x8*)(vkh + bo + 256);
            const s16x8 bl0 = *(const s16x8*)(vkl + bo);
            const s16x8 bl1 = *(const s16x8*)(vkl + bo + 256);
            if (kk == 1 && kt < 31)
                gll16(sg + (size_t)(kt + 1) * 2048, &sE[(cur ^ 1) * 4096 + tid * 8]);
            acc[0][0] = __builtin_amdgcn_mfma_f32_32x32x16_bf16(ah0, bh0, acc[0][0], 0, 0, 0);
            acc[0][0] = __builtin_amdgcn_mfma_f32_32x32x16_bf16(ah0, bl0, acc[0][0], 0, 0, 0);
            acc[0][0] = __builtin_amdgcn_mfma_f32_32x32x16_bf16(al0, bh0, acc[0][0], 0, 0, 0);
            acc[0][1] = __builtin_amdgcn_mfma_f32_32x32x16_bf16(ah0, bh1, acc[0][1], 0, 0, 0);
            acc[0][1] = __builtin_amdgcn_mfma_f32_32x32x16_bf16(ah0, bl1, acc[0][1], 0, 0, 0);
            acc[0][1] = __builtin_amdgcn_mfma_f32_32x32x16_bf16(al0, bh1, acc[0][1], 0, 0, 0);
            acc[1][0] = __builtin_amdgcn_mfma_f32_32x32x16_bf16(ah1, bh0, acc[1][0], 0, 0, 0);
            acc[1][0] = __builtin_amdgcn_mfma_f32_32x32x16_bf16(ah1, bl0, acc[1][0], 0, 0, 0);
            acc[1][0] = __builtin_amdgcn_mfma_f32_32x32x16_bf16(al1, bh0, acc[1][0], 0, 0, 0);
            acc[1][1] = __builtin_amdgcn_mfma_f32_32x32x16_bf16(ah1, bh1, acc[1][1], 0, 0, 0);
            acc[1][1] = __builtin_amdgcn_mfma_f32_32x32x16_bf16(ah1, bl1, acc[1][1], 0, 0, 0);
            acc[1][1] = __builtin_amdgcn_mfma_f32_32x32x16_bf16(al1, bh1, acc[1][1], 0, 0, 0);
        }
        __syncthreads();
    }

    // column (over t) softmax stats
    float cmax[2], cinv[2];
#pragma unroll
    for (int cs = 0; cs < 2; ++cs) {
        float mx = -1e30f;
#pragma unroll
        for (int rs = 0; rs < 2; ++rs)
#pragma unroll
            for (int q = 0; q < 16; ++q) mx = fmaxf(mx, acc[rs][cs][q]);
        mx = fmaxf(mx, __shfl_xor(mx, 32));
        float sm = 0.f;
#pragma unroll
        for (int rs = 0; rs < 2; ++rs)
#pragma unroll
            for (int q = 0; q < 16; ++q) sm += __expf(acc[rs][cs][q] - mx);
        sm += __shfl_xor(sm, 32);
        cmax[cs] = mx; cinv[cs] = 1.0f / sm;
    }
    // per-row: W = exp(5*nsim) = se^5 (unnormalized), DP = sum W*sim, BNUM = sum se
#pragma unroll
    for (int rs = 0; rs < 2; ++rs)
#pragma unroll
        for (int q = 0; q < 16; ++q) {
            const int t = (rs << 5) + (q & 3) + ((q >> 2) << 3) + (h << 2);
            float dp = 0.f, bn = 0.f;
#pragma unroll
            for (int cs = 0; cs < 2; ++cs) {
                const float sim = acc[rs][cs][q];
                const float ns = __expf(sim - cmax[cs]) * cinv[cs];
                const float se = __expf(ns);
                float w5 = se * se; w5 = w5 * w5; w5 *= se;
                dp += w5 * sim; bn += se;
                const int r = rbase + (cs << 5);
                const short hs = f2bf(w5);
                Wh[(size_t)t * 1024 + r] = hs;
                Wl[(size_t)t * 1024 + r] = f2bf(w5 - bf2f(hs));
            }
#pragma unroll
            for (int off = 16; off; off >>= 1) {
                dp += __shfl_xor(dp, off);
                bn += __shfl_xor(bn, off);
            }
            if (l31 == 0) {
                atomicAdd(&ws[P3_DP + (size_t)p * 64 + t], dp);
                ws[P3_BNUM + (size_t)p * 1024 + t * 16 + (rh << 3) + w] = bn;
            }
        }
}

// |W @ v|^2 row norms. grid 512 = (a,tm,dh); 512 threads; B from VTF; A via LDS+gll.
__global__ __launch_bounds__(512, 4)
void stageB3(float* __restrict__ ws)
{
    __shared__ short sW[2 * 4096];
    const int tid = threadIdx.x;
    const int xcd = blockIdx.x & 7, slot = blockIdx.x >> 3;
    const int a = (xcd << 1) | (slot >> 5);
    const int tm = (slot >> 1) & 15;
    const int dh = slot & 1;
    const int p = a * 16 + tm;
    const int w = tid >> 6, l31 = tid & 31, h = (tid >> 5) & 1;

    const short* __restrict__ vth = (const short*)(ws + P3_VTFH) + (size_t)a * 1048576;
    const short* __restrict__ vtl = (const short*)(ws + P3_VTFL) + (size_t)a * 1048576;
    const short* __restrict__ Wh = (const short*)(ws + P3_WH) + ((size_t)p << 16);
    const short* __restrict__ Wl = (const short*)(ws + P3_WL) + ((size_t)p << 16);

    const int s_pl = tid >> 8, rest = tid & 255;
    const int s_u = (rest >> 6) & 3, s_t = rest & 63;
    const short* sg = (s_pl ? Wl : Wh) + (size_t)s_t * 1024 + s_u * 8;  // + kt*32
    const int dbase = (dh << 9) + (w << 6) + l31;

    f32x16 acc[2][2] = {};
    gll16(sg, &sW[tid * 8]);
    __syncthreads();

    for (int kt = 0; kt < 32; ++kt) {
        const int cur = kt & 1;
        const short* vkh = vth + (size_t)kt * 32768;
        const short* vkl = vtl + (size_t)kt * 32768;
#pragma unroll
        for (int kk = 0; kk < 2; ++kk) {
            const int u = (kk << 1) + h;
            const int ao = cur * 4096 + u * 512 + l31 * 8;
            const s16x8 ah0 = *(const s16x8*)&sW[ao];
            const s16x8 ah1 = *(const s16x8*)&sW[ao + 256];
            const s16x8 al0 = *(const s16x8*)&sW[ao + 2048];
            const s16x8 al1 = *(const s16x8*)&sW[ao + 2304];
            const size_t bo = (size_t)u * 8192 + (size_t)dbase * 8;
            const s16x8 bh0 = *(const s16x8*)(vkh + bo);
            const s16x8 bh1 = *(const s16x8*)(vkh + bo + 256);
            const s16x8 bl0 = *(const s16x8*)(vkl + bo);
            const s16x8 bl1 = *(const s16x8*)(vkl + bo + 256);
            if (kk == 1 && kt < 31)
                gll16(sg + (size_t)(kt + 1) * 32, &sW[(cur ^ 1) * 4096 + tid * 8]);
            acc[0][0] = __builtin_amdgcn_mfma_f32_32x32x16_bf16(ah0, bh0, acc[0][0], 0, 0, 0);
            acc[0][0] = __builtin_amdgcn_mfma_f32_32x32x16_bf16(ah0, bl0, acc[0][0], 0, 0, 0);
            acc[0][0] = __builtin_amdgcn_mfma_f32_32x32x16_bf16(al0, bh0, acc[0][0], 0, 0, 0);
            acc[0][1] = __builtin_amdgcn_mfma_f32_32x32x16_bf16(ah0, bh1, acc[0][1], 0, 0, 0);
            acc[0][1] = __builtin_amdgcn_mfma_f32_32x32x16_bf16(ah0, bl1, acc[0][1], 0, 0, 0);
            acc[0][1] = __builtin_amdgcn_mfma_f32_32x32x16_bf16(al0, bh1, acc[0][1], 0, 0, 0);
            acc[1][0] = __builtin_amdgcn_mfma_f32_32x32x16_bf16(ah1, bh0, acc[1][0], 0, 0, 0);
            acc[1][0] = __builtin_amdgcn_mfma_f32_32x32x16_bf16(ah1, bl0, acc[1][0], 0, 0, 0);
            acc[1][0] = __builtin_amdgcn_mfma_f32_32x32x16_bf16(al1, bh0, acc[1][0], 0, 0, 0);
            acc[1][1] = __builtin_amdgcn_mfma_f32_32x32x16_bf16(ah1, bh1, acc[1][1], 0, 0, 0);
            acc[1][1] = __builtin_amdgcn_mfma_f32_32x32x16_bf16(ah1, bl1, acc[1][1], 0, 0, 0);
            acc[1][1] = __builtin_amdgcn_mfma_f32_32x32x16_bf16(al1, bh1, acc[1][1], 0, 0, 0);
        }
        __syncthreads();
    }
#pragma unroll
    for (int rs = 0; rs < 2; ++rs)
#pragma unroll
        for (int q = 0; q < 16; ++q) {
            const int t = (rs << 5) + (q & 3) + ((q >> 2) << 3) + (h << 2);
            float x = acc[rs][0][q] * acc[rs][0][q] + acc[rs][1][q] * acc[rs][1][q];
#pragma unroll
            for (int off = 16; off; off >>= 1) x += __shfl_xor(x, off);
            if (l31 == 0) atomicAdd(&ws[P3_NSQ + (size_t)p * 64 + t], x);
        }
}

// beta from BNUM; e_prime + EPN2. grid 256 (pairs), 256 threads.
__global__ __launch_bounds__(256)
void tail1_3(const float* __restrict__ E, float* __restrict__ ws)
{
    __shared__ float sbn[1024];
    __shared__ float sbs[16];
    __shared__ float s_beta[1024];
    __shared__ float e_lds[64 * 128];
    __shared__ float s_eps[16];
    const int tid = threadIdx.x, p = blockIdx.x, bb = p & 15;
#pragma unroll
    for (int i = 0; i < 4; ++i)
        sbn[tid + (i << 8)] = ws[P3_BNUM + (size_t)p * 1024 + tid + (i << 8)];
    if (tid < 16) s_eps[tid] = 0.f;
    __syncthreads();
    if (tid < 16) {
        float s = 0.f;
        for (int t = 0; t < 64; ++t) s += sbn[t * 16 + tid];
        sbs[tid] = s;
    }
    __syncthreads();
#pragma unroll
    for (int i = 0; i < 4; ++i) {
        const int idx = tid + (i << 8);
        const float bv = sbn[idx] / sbs[idx & 15];
        s_beta[idx] = bv;
        ws[P3_BETA + (size_t)p * 1024 + idx] = bv;
    }
    const int dl = tid >> 1, m0 = (tid & 1) * 8;
    float s2[8] = {0.f, 0.f, 0.f, 0.f, 0.f, 0.f, 0.f, 0.f};
    for (int ch = 0; ch < 8; ++ch) {
        const int d0 = ch << 7;
        __syncthreads();
#pragma unroll
        for (int i = 0; i < 8; ++i) {
            const int u = tid + (i << 8);
            const int row = u >> 5, q = u & 31;
            *(float4*)&e_lds[row * 128 + q * 4] =
                *(const float4*)(E + (size_t)(bb * 64 + row) * 1024 + d0 + q * 4);
        }
        __syncthreads();
        float s[8] = {0.f, 0.f, 0.f, 0.f, 0.f, 0.f, 0.f, 0.f};
        for (int t = 0; t < 64; ++t) {
            const float ev = e_lds[t * 128 + dl];
#pragma unroll
            for (int j = 0; j < 8; ++j) s[j] = fmaf(ev, s_beta[t * 16 + m0 + j], s[j]);
        }
        float4 lo = {s[0], s[1], s[2], s[3]}, hi = {s[4], s[5], s[6], s[7]};
        float* epr = ws + P3_EP + (size_t)p * 16384 + (size_t)(d0 + dl) * 16 + m0;
        *(float4*)epr = lo; *(float4*)(epr + 4) = hi;
#pragma unroll
        for (int j = 0; j < 8; ++j) s2[j] += s[j] * s[j];
    }
#pragma unroll
    for (int j = 0; j < 8; ++j) atomicAdd(&s_eps[m0 + j], s2[j]);
    __syncthreads();
    if (tid < 16) ws[P3_EPN2 + (size_t)p * 16 + tid] = s_eps[tid];
}

// cos2 accumulation into REF. grid 256 = (a, m); 256 threads.
__global__ __launch_bounds__(256)
void tail2_3(const float* __restrict__ Vb, float* __restrict__ ws)
{
    __shared__ float lds_ep[16 * 1024];
    const int tid = threadIdx.x;
    const int L = (int)(blockIdx.x >> 3) + (int)(blockIdx.x & 7) * 32;
    const int a = L >> 4, m = L & 15;
    const int w = tid >> 6, lane = tid & 63;
    for (int idx = tid; idx < 16384; idx += 256) {
        const int bbi = idx >> 10, d = idx & 1023;
        lds_ep[idx] = ws[P3_EP + (size_t)(a * 16 + bbi) * 16384 + (size_t)d * 16 + m];
    }
    __syncthreads();
    for (int i = 0; i < 16; ++i) {
        const int r = m * 64 + w * 16 + i;
        const float* vr = Vb + (size_t)(a * 1024 + r) * 1024;
        float vv[16];
#pragma unroll
        for (int k = 0; k < 16; ++k) vv[k] = vr[lane + (k << 6)];
        const float vn = ws[P3_VN2 + (size_t)a * 1024 + r];
#pragma unroll
        for (int bbi = 0; bbi < 16; ++bbi) {
            float dot = 0.f;
#pragma unroll
            for (int k = 0; k < 16; ++k)
                dot = fmaf(vv[k], lds_ep[bbi * 1024 + lane + (k << 6)], dot);
#pragma unroll
            for (int off = 32; off; off >>= 1) dot += __shfl_xor(dot, off);
            if (lane == 0) {
                const float ep2 = ws[P3_EPN2 + (size_t)(a * 16 + bbi) * 16 + m];
                const float c2 = dot / (sqrtf(vn) * sqrtf(ep2));
                atomicAdd(&ws[P3_REF + (size_t)(a * 16 + bbi) * 16 + m], c2 * (1.0f / 64.0f));
            }
        }
    }
}

__global__ __launch_bounds__(256)
void finalize3(const float* __restrict__ ws, float* __restrict__ out)
{
    __shared__ float s_es[256];
    __shared__ float sbeta[1024];
    __shared__ float s_acc[256];
    __shared__ float s_out[2];
    const int tid = threadIdx.x;
    {
        const int p = tid, bb = p & 15;
        float s1 = 0.f;
        for (int t = 0; t < 64; ++t) {
            const float dp = ws[P3_DP + (size_t)p * 64 + t];
            const float nq = ws[P3_NSQ + (size_t)p * 64 + t];
            const float en = ws[P3_EN2 + (size_t)bb * 64 + t];
            s1 += dp / (sqrtf(nq) * sqrtf(en));
        }
        float s2 = 0.f;
        for (int mm = 0; mm < 16; ++mm) s2 += __expf(ws[P3_REF + (size_t)p * 16 + mm]);
        const float S = logf(s1) / G2 + logf(s2) / G2;
        s_es[p] = G3 * __expf(S);
    }
    __syncthreads();
    if (tid == 0) {
        float l = 0.f;
        for (int i = 0; i < 16; ++i) {
            float rs = 0.f, cs = 0.f;
            for (int j = 0; j < 16; ++j) { rs += s_es[i * 16 + j]; cs += s_es[j * 16 + i]; }
            const float num = s_es[i * 16 + i];
            l -= num / rs;
            l -= num / cs;
        }
        s_out[0] = l; s_out[1] = 0.f;
    }
    for (int i = 0; i < 16; ++i) {
        for (int idx = tid; idx < 1024; idx += 256)
            sbeta[idx] = ws[P3_BETA + (size_t)(i * 17) * 1024 + idx];
        __syncthreads();
        float part = 0.f;
        for (int idx = tid; idx < 4096; idx += 256) {
            const int t = idx >> 6, s = idx & 63;
            float bt = 0.f, ds = 0.f;
            for (int mm = 0; mm < 16; ++mm) {
                bt += sbeta[t * 16 + mm] * sbeta[s * 16 + mm];
                ds += sbeta[s * 16 + mm] * sbeta[s * 16 + mm];
            }
            const float df = bt - ds;
            part += df * df;
        }
        s_acc[tid] = part;
        __syncthreads();
        if (tid == 0) {
            float tot = 0.f;
            for (int j = 0; j < 256; ++j) tot += s_acc[j];
            s_out[1] += sqrtf(tot);
        }
        __syncthreads();
    }
    if (tid == 0) out[0] = s_out[0] + s_out[1];
}

// ============================ ROUND-2 PATH (fallback, verified) ============================

__global__ __launch_bounds__(256)
void split_kernel(const float* __restrict__ E, const float* __restrict__ Vb,
                  float* __restrict__ ws)
{
    const int tid = threadIdx.x, b = blockIdx.x;
    const int sub = tid >> 5, lane32 = tid & 31;
    const float* src; short* dh; short* dl; float* nout; int row;
    if (b < 2048) {
        row = b * 8 + sub;
        src = Vb + (size_t)row * 1024;
        dh = (short*)(ws + O_VH) + (size_t)row * 1024;
        dl = (short*)(ws + O_VL) + (size_t)row * 1024;
        nout = ws + O_VN2 + row;
    } else {
        row = (b - 2048) * 8 + sub;
        src = E + (size_t)row * 1024;
        dh = (short*)(ws + O_EH) + (size_t)row * 1024;
        dl = (short*)(ws + O_EL) + (size_t)row * 1024;
        nout = ws + O_EN2 + row;
    }
    float nrm = 0.f;
#pragma unroll
    for (int i = 0; i < 8; ++i) {
        const int c = lane32 * 4 + i * 128;
        float4 f = *(const float4*)(src + c);
        short4 hs, ls;
        hs.x = f2bf(f.x); ls.x = f2bf(f.x - bf2f(hs.x));
        hs.y = f2bf(f.y); ls.y = f2bf(f.y - bf2f(hs.y));
        hs.z = f2bf(f.z); ls.z = f2bf(f.z - bf2f(hs.z));
        hs.w = f2bf(f.w); ls.w = f2bf(f.w - bf2f(hs.w));
        *(short4*)(dh + c) = hs;
        *(short4*)(dl + c) = ls;
        nrm += f.x*f.x + f.y*f.y + f.z*f.z + f.w*f.w;
    }
#pragma unroll
    for (int off = 16; off; off >>= 1) nrm += __shfl_xor(nrm, off);
    if (lane32 == 0) *nout = nrm;
}

__global__ __launch_bounds__(512, 2)
void stageA_kernel(float* __restrict__ ws)
{
    __shared__ short sE[2][64 * 32];
    __shared__ short sV[2][1024 * 32];
    __shared__ float sZw[512], sDw[512], s_bnum[1024], s_bsum[16], s_invZ[64];

    const int tid = threadIdx.x;
    const int L = (int)(blockIdx.x >> 3) + (int)(blockIdx.x & 7) * 32;
    const int p = L, a = p >> 4, bb = p & 15;
    const int w = tid >> 6, lane = tid & 63, l31 = lane & 31, h = lane >> 5;

    const short* vhp = (const short*)(ws + O_VH) + (size_t)a * (1024 * 1024);
    const short* vlp = (const short*)(ws + O_VL) + (size_t)a * (1024 * 1024);
    const short* ehp = (const short*)(ws + O_EH) + (size_t)bb * (64 * 1024);
    const short* elp = (const short*)(ws + O_EL) + (size_t)bb * (64 * 1024);
    float* attnp = ws + O_ATTN + (size_t)p * 65536;

    f32x16 acc[2][4] = {};

    for (int kt = 0; kt < 32; ++kt) {
        const int k0 = kt << 5;
        {
            const int pp = tid >> 8, row = (tid >> 2) & 63, q = tid & 3;
            const short* g = pp ? elp : ehp;
            s16x8 dvec = *(const s16x8*)(g + (size_t)row * 1024 + k0 + (q << 3));
            *(s16x8*)&sE[pp][(row << 5) + ((q ^ (row & 3)) << 3)] = dvec;
        }
#pragma unroll
        for (int pp = 0; pp < 2; ++pp) {
            const short* g = pp ? vlp : vhp;
#pragma unroll
            for (int i = 0; i < 8; ++i) {
                const int u = tid + (i << 9);
                const int row = u >> 2, q = u & 3;
                s16x8 dvec = *(const s16x8*)(g + (size_t)row * 1024 + k0 + (q << 3));
                *(s16x8*)&sV[pp][(row << 5) + ((q ^ (row & 3)) << 3)] = dvec;
            }
        }
        __syncthreads();
#pragma unroll
        for (int kk = 0; kk < 2; ++kk) {
            const int unit = (kk << 1) + h;
            s16x8 ah[2], al[2];
#pragma unroll
            for (int rs = 0; rs < 2; ++rs) {
                const int row = (rs << 5) + l31;
                const int off = (row << 5) + ((unit ^ (row & 3)) << 3);
                ah[rs] = *(const s16x8*)&sE[0][off];
                al[rs] = *(const s16x8*)&sE[1][off];
            }
#pragma unroll
            for (int cs = 0; cs < 4; ++cs) {
                const int r = (w << 7) + (cs << 5) + l31;
                const int off = (r << 5) + ((unit ^ (r & 3)) << 3);
                const s16x8 bh = *(const s16x8*)&sV[0][off];
                const s16x8 bl = *(const s16x8*)&sV[1][off];
#pragma unroll
                for (int rs = 0; rs < 2; ++rs) {
                    acc[rs][cs] = __builtin_amdgcn_mfma_f32_32x32x16_bf16(ah[rs], bh, acc[rs][cs], 0, 0, 0);
                    acc[rs][cs] = __builtin_amdgcn_mfma_f32_32x32x16_bf16(ah[rs], bl, acc[rs][cs], 0, 0, 0);
                    acc[rs][cs] = __builtin_amdgcn_mfma_f32_32x32x16_bf16(al[rs], bh, acc[rs][cs], 0, 0, 0);
                }
            }
        }
        __syncthreads();
    }

    float cmax[4], cinv[4];
#pragma unroll
    for (int cs = 0; cs < 4; ++cs) {
        float mx = -1e30f;
#pragma unroll
        for (int rs = 0; rs < 2; ++rs)
#pragma unroll
            for (int q = 0; q < 16; ++q) mx = fmaxf(mx, acc[rs][cs][q]);
        mx = fmaxf(mx, __shfl_xor(mx, 32));
        float sm = 0.f;
#pragma unroll
        for (int rs = 0; rs < 2; ++rs)
#pragma unroll
            for (int q = 0; q < 16; ++q) sm += __expf(acc[rs][cs][q] - mx);
        sm += __shfl_xor(sm, 32);
        cmax[cs] = mx; cinv[cs] = 1.0f / sm;
    }
#pragma unroll
    for (int rs = 0; rs < 2; ++rs) {
#pragma unroll
        for (int q = 0; q < 16; ++q) {
            float zp = 0.f, dp = 0.f, bn0 = 0.f, bn1 = 0.f;
#pragma unroll
            for (int cs = 0; cs < 4; ++cs) {
                const float sim = acc[rs][cs][q];
                const float ns = __expf(sim - cmax[cs]) * cinv[cs];
                const float se = __expf(ns);
                float w5 = se * se; w5 = w5 * w5; w5 *= se;
                zp += w5; dp += w5 * sim;
                if (cs < 2) bn0 += se; else bn1 += se;
                acc[rs][cs][q] = w5;
            }
#pragma unroll
            for (int off = 16; off; off >>= 1) {
                zp  += __shfl_xor(zp, off);
                dp  += __shfl_xor(dp, off);
                bn0 += __shfl_xor(bn0, off);
                bn1 += __shfl_xor(bn1, off);
            }
            if (l31 == 0) {
                const int t = (rs << 5) + (q & 3) + ((q >> 2) << 3) + (h << 2);
                sZw[(w << 6) + t] = zp;
                sDw[(w << 6) + t] = dp;
                s_bnum[(t << 4) + (w << 1)]     = bn0;
                s_bnum[(t << 4) + (w << 1) + 1] = bn1;
            }
        }
    }
    __syncthreads();
    if (tid < 64) {
        float Z = 0.f, dv = 0.f;
#pragma unroll
        for (int ww = 0; ww < 8; ++ww) { Z += sZw[(ww << 6) + tid]; dv += sDw[(ww << 6) + tid]; }
        s_invZ[tid] = 1.0f / Z;
        ws[O_DOTVE + (size_t)p * 64 + tid] = dv / Z;
        ws[O_NSQ   + (size_t)p * 64 + tid] = 0.f;
    }
    if (tid >= 64 && tid < 80) ws[O_REF + (size_t)p * 16 + (tid - 64)] = 0.f;
    if (tid >= 128 && tid < 144) {
        float s = 0.f;
        for (int t = 0; t < 64; ++t) s += s_bnum[(t << 4) + (tid - 128)];
        s_bsum[tid - 128] = s;
    }
    __syncthreads();
    for (int idx = tid; idx < 1024; idx += 512)
        ws[O_BETA + (size_t)p * 1024 + idx] = s_bnum[idx] / s_bsum[idx & 15];
#pragma unroll
    for (int rs = 0; rs < 2; ++rs)
#pragma unroll
        for (int q = 0; q < 16; ++q) {
            const int t = (rs << 5) + (q & 3) + ((q >> 2) << 3) + (h << 2);
            const float iz = s_invZ[t];
#pragma unroll
            for (int cs = 0; cs < 4; ++cs) {
                const int r = (w << 7) + (cs << 5) + l31;
                attnp[(size_t)t * 1024 + r] = acc[rs][cs][q] * iz;
            }
        }
}

__global__ __launch_bounds__(256, 2)
void stageB_kernel(float* __restrict__ ws)
{
    __shared__ short sA[2][128 * 32];
    __shared__ short sB[2][128 * 32];
    const int tid = threadIdx.x;
    const int L = (int)(blockIdx.x >> 3) + (int)(blockIdx.x & 7) * 128;
    const int a = L >> 6, tile = L & 63, tm = tile >> 3, tn = tile & 7;
    const int lane = tid & 63, l31 = lane & 31, h = lane >> 5;
    const int w = tid >> 6;
    const int rw = w & 1, cw = w >> 1;
    const float* attn_a = ws + O_ATTN + (size_t)a * 1048576;
    const short* vhp = (const short*)(ws + O_VH) + (size_t)a * (1024 * 1024);
    const short* vlp = (const short*)(ws + O_VL) + (size_t)a * (1024 * 1024);
    const int dqt = tid & 31, rqt = tid >> 5;
    f32x16 acc[2][2] = {};

    for (int rk = 0; rk < 32; ++rk) {
        const int r0 = rk << 5;
#pragma unroll
        for (int i = 0; i < 4; ++i) {
            const int u = tid + (i << 8);
            const int row = u >> 3, q = u & 7;
            const float4 f = *(const float4*)(attn_a + (size_t)(tm * 128 + row) * 1024 + r0 + (q << 2));
            short4 hs, ls;
            hs.x = f2bf(f.x); ls.x = f2bf(f.x - bf2f(hs.x));
            hs.y = f2bf(f.y); ls.y = f2bf(f.y - bf2f(hs.y));
            hs.z = f2bf(f.z); ls.z = f2bf(f.z - bf2f(hs.z));
            hs.w = f2bf(f.w); ls.w = f2bf(f.w - bf2f(hs.w));
            const int off = (row << 5) + ((((q >> 1) ^ (row & 3))) << 3) + ((q & 1) << 2);
            *(short4*)&sA[0][off] = hs;
            *(short4*)&sA[1][off] = ls;
        }
#pragma unroll
        for (int pp = 0; pp < 2; ++pp) {
            const short* g = pp ? vlp : vhp;
            short4 in0 = *(const short4*)(g + (size_t)(r0 + rqt * 4 + 0) * 1024 + tn * 128 + dqt * 4);
            short4 in1 = *(const short4*)(g + (size_t)(r0 + rqt * 4 + 1) * 1024 + tn * 128 + dqt * 4);
            short4 in2 = *(const short4*)(g + (size_t)(r0 + rqt * 4 + 2) * 1024 + tn * 128 + dqt * 4);
            short4 in3 = *(const short4*)(g + (size_t)(r0 + rqt * 4 + 3) * 1024 + tn * 128 + dqt * 4);
            short4 o0 = {in0.x, in1.x, in2.x, in3.x};
            short4 o1 = {in0.y, in1.y, in2.y, in3.y};
            short4 o2 = {in0.z, in1.z, in2.z, in3.z};
            short4 o3 = {in0.w, in1.w, in2.w, in3.w};
            {   const int d = dqt * 4 + 0;
                *(short4*)&sB[pp][(d << 5) + (((rqt >> 1) ^ ((d >> 2) & 3)) << 3) + ((rqt & 1) << 2)] = o0; }
            {   const int d = dqt * 4 + 1;
                *(short4*)&sB[pp][(d << 5) + (((rqt >> 1) ^ ((d >> 2) & 3)) << 3) + ((rqt & 1) << 2)] = o1; }
            {   const int d = dqt * 4 + 2;
                *(short4*)&sB[pp][(d << 5) + (((rqt >> 1) ^ ((d >> 2) & 3)) << 3) + ((rqt & 1) << 2)] = o2; }
            {   const int d = dqt * 4 + 3;
                *(short4*)&sB[pp][(d << 5) + (((rqt >> 1) ^ ((d >> 2) & 3)) << 3) + ((rqt & 1) << 2)] = o3; }
        }
        __syncthreads();
#pragma unroll
        for (int kk = 0; kk < 2; ++kk) {
            const int unit = (kk << 1) + h;
            s16x8 ah[2], al[2];
#pragma unroll
            for (int rs = 0; rs < 2; ++rs) {
                const int row = rw * 64 + rs * 32 + l31;
                const int off = (row << 5) + ((unit ^ (row & 3)) << 3);
                ah[rs] = *(const s16x8*)&sA[0][off];
                al[rs] = *(const s16x8*)&sA[1][off];
            }
#pragma unroll
            for (int cs = 0; cs < 2; ++cs) {
                const int d = cw * 64 + cs * 32 + l31;
                const int off = (d << 5) + ((unit ^ ((d >> 2) & 3)) << 3);
                const s16x8 bh = *(const s16x8*)&sB[0][off];
                const s16x8 bl = *(const s16x8*)&sB[1][off];
#pragma unroll
                for (int rs = 0; rs < 2; ++rs) {
                    acc[rs][cs] = __builtin_amdgcn_mfma_f32_32x32x16_bf16(ah[rs], bh, acc[rs][cs], 0, 0, 0);
                    acc[rs][cs] = __builtin_amdgcn_mfma_f32_32x32x16_bf16(ah[rs], bl, acc[rs][cs], 0, 0, 0);
                    acc[rs][cs] = __builtin_amdgcn_mfma_f32_32x32x16_bf16(al[rs], bh, acc[rs][cs], 0, 0, 0);
                }
            }
        }
        __syncthreads();
    }
#pragma unroll
    for (int rs = 0; rs < 2; ++rs) {
#pragma unroll
        for (int q = 0; q < 16; ++q) {
            float x = acc[rs][0][q] * acc[rs][0][q] + acc[rs][1][q] * acc[rs][1][q];
#pragma unroll
            for (int off = 16; off; off >>= 1) x += __shfl_xor(x, off);
            if (l31 == 0) {
                const int t_local = rw * 64 + rs * 32 + (q & 3) + ((q >> 2) << 3) + (h << 2);
                atomicAdd(&ws[O_NSQ + (size_t)a * 1024 + tm * 128 + t_local], x);
            }
        }
    }
}

__global__ __launch_bounds__(256)
void tail1_kernel(const float* __restrict__ E, float* __restrict__ ws)
{
    __shared__ float s_beta[1024];
    __shared__ float e_lds[64 * 128];
    __shared__ float s_eps[16];
    const int tid = threadIdx.x, p = blockIdx.x, bb = p & 15;
#pragma unroll
    for (int i = 0; i < 4; ++i)
        s_beta[tid + (i << 8)] = ws[O_BETA + (size_t)p * 1024 + tid + (i << 8)];
    if (tid < 16) s_eps[tid] = 0.f;
    const int dl = tid >> 1, m0 = (tid & 1) * 8;
    float s2[8] = {0.f,0.f,0.f,0.f,0.f,0.f,0.f,0.f};
    for (int ch = 0; ch < 8; ++ch) {
        const int d0 = ch << 7;
        __syncthreads();
#pragma unroll
        for (int i = 0; i < 8; ++i) {
            const int u = tid + (i << 8);
            const int row = u >> 5, q = u & 31;
            *(float4*)&e_lds[row * 128 + q * 4] =
                *(const float4*)(E + (size_t)(bb * 64 + row) * 1024 + d0 + q * 4);
        }
        __syncthreads();
        float s[8] = {0.f,0.f,0.f,0.f,0.f,0.f,0.f,0.f};
        for (int t = 0; t < 64; ++t) {
            const float ev = e_lds[t * 128 + dl];
#pragma unroll
            for (int j = 0; j < 8; ++j) s[j] = fmaf(ev, s_beta[t * 16 + m0 + j], s[j]);
        }
        float4 lo = {s[0], s[1], s[2], s[3]}, hi = {s[4], s[5], s[6], s[7]};
        float* epr = ws + O_EP + (size_t)p * 16384 + (size_t)(d0 + dl) * 16 + m0;
        *(float4*)epr = lo; *(float4*)(epr + 4) = hi;
#pragma unroll
        for (int j = 0; j < 8; ++j) s2[j] += s[j] * s[j];
    }
#pragma unroll
    for (int j = 0; j < 8; ++j) atomicAdd(&s_eps[m0 + j], s2[j]);
    __syncthreads();
    if (tid < 16) ws[O_EPN2 + (size_t)p * 16 + tid] = s_eps[tid];
}

__global__ __launch_bounds__(256)
void tail2_kernel(const float* __restrict__ Vb, float* __restrict__ ws)
{
    __shared__ float lds_ep[16 * 1024];
    const int tid = threadIdx.x;
    const int L = (int)(blockIdx.x >> 3) + (int)(blockIdx.x & 7) * 32;
    const int a = L >> 4, m = L & 15;
    const int w = tid >> 6, lane = tid & 63;
    for (int idx = tid; idx < 16384; idx += 256) {
        const int bbi = idx >> 10, d = idx & 1023;
        lds_ep[idx] = ws[O_EP + (size_t)(a * 16 + bbi) * 16384 + (size_t)d * 16 + m];
    }
    __syncthreads();
    for (int i = 0; i < 16; ++i) {
        const int r = m * 64 + w * 16 + i;
        const float* vr = Vb + (size_t)(a * 1024 + r) * 1024;
        float vv[16];
#pragma unroll
        for (int k = 0; k < 16; ++k) vv[k] = vr[lane + (k << 6)];
        const float vn = ws[O_VN2 + a * 1024 + r];
#pragma unroll
        for (int bbi = 0; bbi < 16; ++bbi) {
            float dot = 0.f;
#pragma unroll
            for (int k = 0; k < 16; ++k) dot = fmaf(vv[k], lds_ep[bbi * 1024 + lane + (k << 6)], dot);
#pragma unroll
            for (int off = 32; off; off >>= 1) dot += __shfl_xor(dot, off);
            if (lane == 0) {
                const float ep2 = ws[O_EPN2 + (size_t)(a * 16 + bbi) * 16 + m];
                const float c2 = dot / (sqrtf(vn) * sqrtf(ep2));
                atomicAdd(&ws[O_REF + (size_t)(a * 16 + bbi) * 16 + m], c2 * (1.0f / 64.0f));
            }
        }
    }
}

__global__ __launch_bounds__(256)
void finalize2_kernel(const float* __restrict__ ws, float* __restrict__ out)
{
    __shared__ float s_es[256];
    __shared__ float sbeta[1024];
    __shared__ float s_acc[256];
    __shared__ float s_out[2];
    const int tid = threadIdx.x;
    {
        const int p = tid, bb = p & 15;
        float s1 = 0.f;
        for (int t = 0; t < 64; ++t) {
            const float dv = ws[O_DOTVE + (size_t)p * 64 + t];
            const float nq = ws[O_NSQ + (size_t)p * 64 + t];
            const float en = ws[O_EN2 + bb * 64 + t];
            s1 += dv / (sqrtf(nq) * sqrtf(en));
        }
        float s2 = 0.f;
        for (int mm = 0; mm < 16; ++mm) s2 += __expf(ws[O_REF + (size_t)p * 16 + mm]);
        const float S = logf(s1) / G2 + logf(s2) / G2;
        s_es[p] = G3 * __expf(S);
    }
    __syncthreads();
    if (tid == 0) {
        float l = 0.f;
        for (int i = 0; i < 16; ++i) {
            float rs = 0.f, cs = 0.f;
            for (int j = 0; j < 16; ++j) { rs += s_es[i * 16 + j]; cs += s_es[j * 16 + i]; }
            const float num = s_es[i * 16 + i];
            l -= num / rs;
            l -= num / cs;
        }
        s_out[0] = l; s_out[1] = 0.f;
    }
    for (int i = 0; i < 16; ++i) {
        for (int idx = tid; idx < 1024; idx += 256)
            sbeta[idx] = ws[O_BETA + (size_t)(i * 17) * 1024 + idx];
        __syncthreads();
        float part = 0.f;
        for (int idx = tid; idx < 4096; idx += 256) {
            const int t = idx >> 6, s = idx & 63;
            float bt = 0.f, ds = 0.f;
            for (int mm = 0; mm < 16; ++mm) {
                bt += sbeta[t * 16 + mm] * sbeta[s * 16 + mm];
                ds += sbeta[s * 16 + mm] * sbeta[s * 16 + mm];
            }
            const float df = bt - ds;
            part += df * df;
        }
        s_acc[tid] = part;
        __syncthreads();
        if (tid == 0) {
            float tot = 0.f;
            for (int j = 0; j < 256; ++j) tot += s_acc[j];
            s_out[1] += sqrtf(tot);
        }
        __syncthreads();
    }
    if (tid == 0) out[0] = s_out[0] + s_out[1];
}

// ============================ launch ============================

extern "C" void kernel_launch(void* const* d_in, const int* in_sizes, int n_in,
                              void* d_out, int out_size, void* d_ws, size_t ws_size,
                              hipStream_t stream)
{
    const float* E  = (const float*)d_in[0];
    const float* Vb = (const float*)d_in[1];
    float* ws  = (float*)d_ws;
    float* out = (float*)d_out;

    if (ws_size >= (size_t)P3_TOTAL * 4) {
        hipMemsetAsync((char*)d_ws + P3_ACC * 4, 0, P3_ACCN * 4, stream);
        pack_v3<<<dim3(4096), dim3(256), 0, stream>>>(Vb, ws);
        pack_e3<<<dim3(16), dim3(512), 0, stream>>>(E, ws);
        stageA3<<<dim3(512), dim3(512), 0, stream>>>(ws);
        stageB3<<<dim3(512), dim3(512), 0, stream>>>(ws);
        tail1_3<<<dim3(256), dim3(256), 0, stream>>>(E, ws);
        tail2_3<<<dim3(256), dim3(256), 0, stream>>>(Vb, ws);
        finalize3<<<dim3(1), dim3(256), 0, stream>>>(ws, out);
        return;
    }

    // fallback: round-2 verified path
    split_kernel<<<dim3(2176), dim3(256), 0, stream>>>(E, Vb, ws);
    stageA_kernel<<<dim3(256), dim3(512), 0, stream>>>(ws);
    stageB_kernel<<<dim3(1024), dim3(256), 0, stream>>>(ws);
    tail1_kernel<<<dim3(256), dim3(256), 0, stream>>>(E, ws);
    tail2_kernel<<<dim3(256), dim3(256), 0, stream>>>(Vb, ws);
    finalize2_kernel<<<dim3(1), dim3(256), 0, stream>>>(ws, out);
}

// Round 7
// 539.168 us; speedup vs baseline: 3.1939x; 1.3853x over previous
//
#include <hip/hip_runtime.h>
#include <math.h>

namespace {
constexpr float G1 = 5.0f, G2 = 5.0f, G3 = 10.0f;

// ---------- round-2 (fallback) ws layout ----------
constexpr size_t O_VH    = 0;
constexpr size_t O_VL    = 8388608;
constexpr size_t O_EH    = 16777216;
constexpr size_t O_EL    = 17301504;
constexpr size_t O_ATTN  = 17825792;
constexpr size_t O_BETA  = 34603008;
constexpr size_t O_EP    = 34865152;
constexpr size_t O_DOTVE = 39059456;
constexpr size_t O_NSQ   = 39075840;
constexpr size_t O_EN2   = 39092224;
constexpr size_t O_VN2   = 39093248;
constexpr size_t O_EPN2  = 39109632;
constexpr size_t O_REF   = 39113728;
constexpr size_t WS_TOTAL_F = 39118080;

// ---------- v3 ws layout (floats) ----------
constexpr size_t P3_VFH  = 0;         // V row-frag hi: [a][kt32][u4][r1024]x8sh
constexpr size_t P3_VFL  = 8388608;
constexpr size_t P3_VTFH = 16777216;  // V^T frag hi: [a][ktr32][u4][d1024]x8sh
constexpr size_t P3_VTFL = 25165824;
constexpr size_t P3_EFH  = 33554432;  // E frag hi: [b][kt32][u4][t64]x8sh
constexpr size_t P3_EFL  = 34078720;
constexpr size_t P3_WH   = 34603008;  // W hi: [p][t64][r1024] shorts
constexpr size_t P3_WL   = 42991616;
constexpr size_t P3_ACC  = 51380224;  // zeroed region start
constexpr size_t P3_BNUM = P3_ACC;                // 262144
constexpr size_t P3_DP   = P3_ACC + 262144;       // 16384
constexpr size_t P3_NSQ  = P3_DP + 16384;         // 16384
constexpr size_t P3_REF  = P3_NSQ + 16384;        // 4096
constexpr size_t P3_VN2  = P3_REF + 4096;         // 16384
constexpr size_t P3_EN2  = P3_VN2 + 16384;        // 1024
constexpr size_t P3_ACCN = 316416;                // floats memset to 0
constexpr size_t P3_BETA = P3_ACC + P3_ACCN;      // 262144
constexpr size_t P3_EP   = P3_BETA + 262144;      // 4194304
constexpr size_t P3_EPN2 = P3_EP + 4194304;       // 4096
constexpr size_t P3_ES   = P3_EPN2 + 4096;        // 256  (exp_S per pair)
constexpr size_t P3_RG   = P3_ES + 256;           // 16   (per-i sqrt reg)
constexpr size_t P3_TOTAL = P3_RG + 16;
}

using s16x8  = __attribute__((ext_vector_type(8))) short;
using f32x16 = __attribute__((ext_vector_type(16))) float;

__device__ __forceinline__ short f2bf(float x) {
    unsigned u = __float_as_uint(x);
    unsigned r = (u + 0x7FFFu + ((u >> 16) & 1u)) >> 16;
    return (short)r;
}
__device__ __forceinline__ float bf2f(short h) {
    return __uint_as_float(((unsigned)(unsigned short)h) << 16);
}
__device__ __forceinline__ void gll16(const void* g, void* l) {
    __builtin_amdgcn_global_load_lds(
        (const __attribute__((address_space(1))) void*)g,
        (__attribute__((address_space(3))) void*)l, 16, 0, 0);
}

// ============================ V3 PATH ============================

// Pack V into fragment-major hi/lo planes (row-frags VF and transposed VTF),
// plus per-row norms. grid: a(16) x rb(16) x db(16); 256 threads.
__global__ __launch_bounds__(256)
void pack_v3(const float* __restrict__ Vb, float* __restrict__ ws)
{
    __shared__ float tile[64][68];
    const int tid = threadIdx.x;
    const int a = blockIdx.x >> 8, rb = (blockIdx.x >> 4) & 15, db = blockIdx.x & 15;
    const float* src = Vb + (size_t)(a * 1024 + rb * 64) * 1024 + db * 64;
    {
        const int row = tid >> 2, cq = (tid & 3) << 4;
#pragma unroll
        for (int i = 0; i < 4; ++i) {
            float4 f = *(const float4*)(src + (size_t)row * 1024 + cq + i * 4);
            tile[row][cq + i * 4 + 0] = f.x;
            tile[row][cq + i * 4 + 1] = f.y;
            tile[row][cq + i * 4 + 2] = f.z;
            tile[row][cq + i * 4 + 3] = f.w;
        }
    }
    __syncthreads();
    if (tid < 64) {
        float s = 0.f;
        for (int c = 0; c < 64; ++c) { const float x = tile[tid][c]; s += x * x; }
        atomicAdd(&ws[P3_VN2 + (size_t)a * 1024 + rb * 64 + tid], s);
    }
    short* vfh = (short*)(ws + P3_VFH) + (size_t)a * 1048576;
    short* vfl = (short*)(ws + P3_VFL) + (size_t)a * 1048576;
    short* vth = (short*)(ws + P3_VTFH) + (size_t)a * 1048576;
    short* vtl = (short*)(ws + P3_VTFL) + (size_t)a * 1048576;
#pragma unroll
    for (int jj = 0; jj < 2; ++jj) {              // row-frags
        const int j = tid + (jj << 8);
        const int r = j & 63, ku = j >> 6;
        const int ktl = ku >> 2, u = ku & 3, dl = ktl * 32 + u * 8;
        s16x8 hv, lv;
#pragma unroll
        for (int i = 0; i < 8; ++i) {
            const float x = tile[r][dl + i];
            const short hs = f2bf(x);
            hv[i] = hs; lv[i] = f2bf(x - bf2f(hs));
        }
        const size_t off = ((size_t)((db * 2 + ktl) * 4 + u) * 1024 + rb * 64 + r) * 8;
        *(s16x8*)(vfh + off) = hv;
        *(s16x8*)(vfl + off) = lv;
    }
#pragma unroll
    for (int jj = 0; jj < 2; ++jj) {              // transposed frags
        const int j = tid + (jj << 8);
        const int d = j & 63, ku = j >> 6;
        const int ktl = ku >> 2, ur = ku & 3, rl = ktl * 32 + ur * 8;
        s16x8 hv, lv;
#pragma unroll
        for (int i = 0; i < 8; ++i) {
            const float x = tile[rl + i][d];
            const short hs = f2bf(x);
            hv[i] = hs; lv[i] = f2bf(x - bf2f(hs));
        }
        const size_t off = ((size_t)((rb * 2 + ktl) * 4 + ur) * 1024 + db * 64 + d) * 8;
        *(s16x8*)(vth + off) = hv;
        *(s16x8*)(vtl + off) = lv;
    }
}

// Pack E into EF fragment planes + row norms. grid 16 (b), 512 threads.
__global__ __launch_bounds__(512)
void pack_e3(const float* __restrict__ E, float* __restrict__ ws)
{
    const int tid = threadIdx.x, b = blockIdx.x;
    short* efh = (short*)(ws + P3_EFH);
    short* efl = (short*)(ws + P3_EFL);
#pragma unroll
    for (int jj = 0; jj < 16; ++jj) {
        const int j = tid + (jj << 9);
        const int t = j & 63, ku = j >> 6;          // ku 0..127
        const int kt = ku >> 2, u = ku & 3;
        const float* ep = E + (size_t)b * 65536 + (size_t)t * 1024 + kt * 32 + u * 8;
        float4 f0 = *(const float4*)ep;
        float4 f1 = *(const float4*)(ep + 4);
        float vals[8] = {f0.x, f0.y, f0.z, f0.w, f1.x, f1.y, f1.z, f1.w};
        s16x8 hv, lv;
#pragma unroll
        for (int i = 0; i < 8; ++i) {
            const short hs = f2bf(vals[i]);
            hv[i] = hs; lv[i] = f2bf(vals[i] - bf2f(hs));
        }
        const size_t off = ((size_t)((b * 32 + kt) * 4 + u) * 64 + t) * 8;
        *(s16x8*)(efh + off) = hv;
        *(s16x8*)(efl + off) = lv;
    }
    {   // EN2
        const int t = tid >> 3, g = tid & 7;
        const float* er = E + (size_t)b * 65536 + (size_t)t * 1024 + g * 128;
        float s = 0.f;
#pragma unroll
        for (int i = 0; i < 32; ++i) {
            float4 f = *(const float4*)(er + i * 4);
            s += f.x * f.x + f.y * f.y + f.z * f.z + f.w * f.w;
        }
        s += __shfl_xor(s, 1); s += __shfl_xor(s, 2); s += __shfl_xor(s, 4);
        if (g == 0) atomicAdd(&ws[P3_EN2 + (size_t)b * 64 + t], s);
    }
}

// sim GEMM + fused column softmax -> W (split bf16), DP, BNUM.
// grid 512 = (a,bb,rh); 512 threads; B-frags direct from VF; A via LDS+gll.
__global__ __launch_bounds__(512, 4)
void stageA3(float* __restrict__ ws)
{
    __shared__ short sE[2 * 4096];
    const int tid = threadIdx.x;
    const int xcd = blockIdx.x & 7, slot = blockIdx.x >> 3;
    const int a = (xcd << 1) | (slot >> 5);
    const int bb = (slot >> 1) & 15;
    const int rh = slot & 1;
    const int p = a * 16 + bb;
    const int w = tid >> 6, l31 = tid & 31, h = (tid >> 5) & 1;

    const short* __restrict__ vfh = (const short*)(ws + P3_VFH) + (size_t)a * 1048576;
    const short* __restrict__ vfl = (const short*)(ws + P3_VFL) + (size_t)a * 1048576;
    const short* __restrict__ efh = (const short*)(ws + P3_EFH) + (size_t)bb * 65536;
    const short* __restrict__ efl = (const short*)(ws + P3_EFL) + (size_t)bb * 65536;
    short* __restrict__ Wh = (short*)(ws + P3_WH) + ((size_t)p << 16);
    short* __restrict__ Wl = (short*)(ws + P3_WL) + ((size_t)p << 16);

    const int s_pl = tid >> 8, rest = tid & 255;
    const short* sg = (s_pl ? efl : efh) + (size_t)rest * 8;  // + kt*2048
    const int rbase = (rh << 9) + (w << 6) + l31;

    f32x16 acc[2][2] = {};
    gll16(sg, &sE[tid * 8]);
    __syncthreads();

    for (int kt = 0; kt < 32; ++kt) {
        const int cur = kt & 1;
        const short* vkh = vfh + (size_t)kt * 32768;
        const short* vkl = vfl + (size_t)kt * 32768;
#pragma unroll
        for (int kk = 0; kk < 2; ++kk) {
            const int u = (kk << 1) + h;
            const int ao = cur * 4096 + u * 512 + l31 * 8;
            const s16x8 ah0 = *(const s16x8*)&sE[ao];
            const s16x8 ah1 = *(const s16x8*)&sE[ao + 256];
            const s16x8 al0 = *(const s16x8*)&sE[ao + 2048];
            const s16x8 al1 = *(const s16x8*)&sE[ao + 2304];
            const size_t bo = (size_t)u * 8192 + (size_t)rbase * 8;
            const s16x8 bh0 = *(const s16x8*)(vkh + bo);
            const s16x8 bh1 = *(const s16x8*)(vkh + bo + 256);
            const s16x8 bl0 = *(const s16x8*)(vkl + bo);
            const s16x8 bl1 = *(const s16x8*)(vkl + bo + 256);
            if (kk == 1 && kt < 31)
                gll16(sg + (size_t)(kt + 1) * 2048, &sE[(cur ^ 1) * 4096 + tid * 8]);
            acc[0][0] = __builtin_amdgcn_mfma_f32_32x32x16_bf16(ah0, bh0, acc[0][0], 0, 0, 0);
            acc[0][0] = __builtin_amdgcn_mfma_f32_32x32x16_bf16(ah0, bl0, acc[0][0], 0, 0, 0);
            acc[0][0] = __builtin_amdgcn_mfma_f32_32x32x16_bf16(al0, bh0, acc[0][0], 0, 0, 0);
            acc[0][1] = __builtin_amdgcn_mfma_f32_32x32x16_bf16(ah0, bh1, acc[0][1], 0, 0, 0);
            acc[0][1] = __builtin_amdgcn_mfma_f32_32x32x16_bf16(ah0, bl1, acc[0][1], 0, 0, 0);
            acc[0][1] = __builtin_amdgcn_mfma_f32_32x32x16_bf16(al0, bh1, acc[0][1], 0, 0, 0);
            acc[1][0] = __builtin_amdgcn_mfma_f32_32x32x16_bf16(ah1, bh0, acc[1][0], 0, 0, 0);
            acc[1][0] = __builtin_amdgcn_mfma_f32_32x32x16_bf16(ah1, bl0, acc[1][0], 0, 0, 0);
            acc[1][0] = __builtin_amdgcn_mfma_f32_32x32x16_bf16(al1, bh0, acc[1][0], 0, 0, 0);
            acc[1][1] = __builtin_amdgcn_mfma_f32_32x32x16_bf16(ah1, bh1, acc[1][1], 0, 0, 0);
            acc[1][1] = __builtin_amdgcn_mfma_f32_32x32x16_bf16(ah1, bl1, acc[1][1], 0, 0, 0);
            acc[1][1] = __builtin_amdgcn_mfma_f32_32x32x16_bf16(al1, bh1, acc[1][1], 0, 0, 0);
        }
        __syncthreads();
    }

    // column (over t) softmax stats
    float cmax[2], cinv[2];
#pragma unroll
    for (int cs = 0; cs < 2; ++cs) {
        float mx = -1e30f;
#pragma unroll
        for (int rs = 0; rs < 2; ++rs)
#pragma unroll
            for (int q = 0; q < 16; ++q) mx = fmaxf(mx, acc[rs][cs][q]);
        mx = fmaxf(mx, __shfl_xor(mx, 32));
        float sm = 0.f;
#pragma unroll
        for (int rs = 0; rs < 2; ++rs)
#pragma unroll
            for (int q = 0; q < 16; ++q) sm += __expf(acc[rs][cs][q] - mx);
        sm += __shfl_xor(sm, 32);
        cmax[cs] = mx; cinv[cs] = 1.0f / sm;
    }
    // per-row: W = exp(5*nsim) = se^5 (unnormalized), DP = sum W*sim, BNUM = sum se
#pragma unroll
    for (int rs = 0; rs < 2; ++rs)
#pragma unroll
        for (int q = 0; q < 16; ++q) {
            const int t = (rs << 5) + (q & 3) + ((q >> 2) << 3) + (h << 2);
            float dp = 0.f, bn = 0.f;
#pragma unroll
            for (int cs = 0; cs < 2; ++cs) {
                const float sim = acc[rs][cs][q];
                const float ns = __expf(sim - cmax[cs]) * cinv[cs];
                const float se = __expf(ns);
                float w5 = se * se; w5 = w5 * w5; w5 *= se;
                dp += w5 * sim; bn += se;
                const int r = rbase + (cs << 5);
                const short hs = f2bf(w5);
                Wh[(size_t)t * 1024 + r] = hs;
                Wl[(size_t)t * 1024 + r] = f2bf(w5 - bf2f(hs));
            }
#pragma unroll
            for (int off = 16; off; off >>= 1) {
                dp += __shfl_xor(dp, off);
                bn += __shfl_xor(bn, off);
            }
            if (l31 == 0) {
                atomicAdd(&ws[P3_DP + (size_t)p * 64 + t], dp);
                ws[P3_BNUM + (size_t)p * 1024 + t * 16 + (rh << 3) + w] = bn;
            }
        }
}

// |W @ v|^2 row norms. grid 512 = (a,tm,dh); 512 threads; B from VTF; A via LDS+gll.
__global__ __launch_bounds__(512, 4)
void stageB3(float* __restrict__ ws)
{
    __shared__ short sW[2 * 4096];
    const int tid = threadIdx.x;
    const int xcd = blockIdx.x & 7, slot = blockIdx.x >> 3;
    const int a = (xcd << 1) | (slot >> 5);
    const int tm = (slot >> 1) & 15;
    const int dh = slot & 1;
    const int p = a * 16 + tm;
    const int w = tid >> 6, l31 = tid & 31, h = (tid >> 5) & 1;

    const short* __restrict__ vth = (const short*)(ws + P3_VTFH) + (size_t)a * 1048576;
    const short* __restrict__ vtl = (const short*)(ws + P3_VTFL) + (size_t)a * 1048576;
    const short* __restrict__ Wh = (const short*)(ws + P3_WH) + ((size_t)p << 16);
    const short* __restrict__ Wl = (const short*)(ws + P3_WL) + ((size_t)p << 16);

    const int s_pl = tid >> 8, rest = tid & 255;
    const int s_u = (rest >> 6) & 3, s_t = rest & 63;
    const short* sg = (s_pl ? Wl : Wh) + (size_t)s_t * 1024 + s_u * 8;  // + kt*32
    const int dbase = (dh << 9) + (w << 6) + l31;

    f32x16 acc[2][2] = {};
    gll16(sg, &sW[tid * 8]);
    __syncthreads();

    for (int kt = 0; kt < 32; ++kt) {
        const int cur = kt & 1;
        const short* vkh = vth + (size_t)kt * 32768;
        const short* vkl = vtl + (size_t)kt * 32768;
#pragma unroll
        for (int kk = 0; kk < 2; ++kk) {
            const int u = (kk << 1) + h;
            const int ao = cur * 4096 + u * 512 + l31 * 8;
            const s16x8 ah0 = *(const s16x8*)&sW[ao];
            const s16x8 ah1 = *(const s16x8*)&sW[ao + 256];
            const s16x8 al0 = *(const s16x8*)&sW[ao + 2048];
            const s16x8 al1 = *(const s16x8*)&sW[ao + 2304];
            const size_t bo = (size_t)u * 8192 + (size_t)dbase * 8;
            const s16x8 bh0 = *(const s16x8*)(vkh + bo);
            const s16x8 bh1 = *(const s16x8*)(vkh + bo + 256);
            const s16x8 bl0 = *(const s16x8*)(vkl + bo);
            const s16x8 bl1 = *(const s16x8*)(vkl + bo + 256);
            if (kk == 1 && kt < 31)
                gll16(sg + (size_t)(kt + 1) * 32, &sW[(cur ^ 1) * 4096 + tid * 8]);
            acc[0][0] = __builtin_amdgcn_mfma_f32_32x32x16_bf16(ah0, bh0, acc[0][0], 0, 0, 0);
            acc[0][0] = __builtin_amdgcn_mfma_f32_32x32x16_bf16(ah0, bl0, acc[0][0], 0, 0, 0);
            acc[0][0] = __builtin_amdgcn_mfma_f32_32x32x16_bf16(al0, bh0, acc[0][0], 0, 0, 0);
            acc[0][1] = __builtin_amdgcn_mfma_f32_32x32x16_bf16(ah0, bh1, acc[0][1], 0, 0, 0);
            acc[0][1] = __builtin_amdgcn_mfma_f32_32x32x16_bf16(ah0, bl1, acc[0][1], 0, 0, 0);
            acc[0][1] = __builtin_amdgcn_mfma_f32_32x32x16_bf16(al0, bh1, acc[0][1], 0, 0, 0);
            acc[1][0] = __builtin_amdgcn_mfma_f32_32x32x16_bf16(ah1, bh0, acc[1][0], 0, 0, 0);
            acc[1][0] = __builtin_amdgcn_mfma_f32_32x32x16_bf16(ah1, bl0, acc[1][0], 0, 0, 0);
            acc[1][0] = __builtin_amdgcn_mfma_f32_32x32x16_bf16(al1, bh0, acc[1][0], 0, 0, 0);
            acc[1][1] = __builtin_amdgcn_mfma_f32_32x32x16_bf16(ah1, bh1, acc[1][1], 0, 0, 0);
            acc[1][1] = __builtin_amdgcn_mfma_f32_32x32x16_bf16(ah1, bl1, acc[1][1], 0, 0, 0);
            acc[1][1] = __builtin_amdgcn_mfma_f32_32x32x16_bf16(al1, bh1, acc[1][1], 0, 0, 0);
        }
        __syncthreads();
    }
#pragma unroll
    for (int rs = 0; rs < 2; ++rs)
#pragma unroll
        for (int q = 0; q < 16; ++q) {
            const int t = (rs << 5) + (q & 3) + ((q >> 2) << 3) + (h << 2);
            float x = acc[rs][0][q] * acc[rs][0][q] + acc[rs][1][q] * acc[rs][1][q];
#pragma unroll
            for (int off = 16; off; off >>= 1) x += __shfl_xor(x, off);
            if (l31 == 0) atomicAdd(&ws[P3_NSQ + (size_t)p * 64 + t], x);
        }
}

// beta from BNUM; e_prime + EPN2. grid 256 (pairs), 256 threads.
__global__ __launch_bounds__(256)
void tail1_3(const float* __restrict__ E, float* __restrict__ ws)
{
    __shared__ float sbn[1024];
    __shared__ float sbs[16];
    __shared__ float s_beta[1024];
    __shared__ float e_lds[64 * 128];
    __shared__ float s_eps[16];
    const int tid = threadIdx.x, p = blockIdx.x, bb = p & 15;
#pragma unroll
    for (int i = 0; i < 4; ++i)
        sbn[tid + (i << 8)] = ws[P3_BNUM + (size_t)p * 1024 + tid + (i << 8)];
    if (tid < 16) s_eps[tid] = 0.f;
    __syncthreads();
    if (tid < 16) {
        float s = 0.f;
        for (int t = 0; t < 64; ++t) s += sbn[t * 16 + tid];
        sbs[tid] = s;
    }
    __syncthreads();
#pragma unroll
    for (int i = 0; i < 4; ++i) {
        const int idx = tid + (i << 8);
        const float bv = sbn[idx] / sbs[idx & 15];
        s_beta[idx] = bv;
        ws[P3_BETA + (size_t)p * 1024 + idx] = bv;
    }
    const int dl = tid >> 1, m0 = (tid & 1) * 8;
    float s2[8] = {0.f, 0.f, 0.f, 0.f, 0.f, 0.f, 0.f, 0.f};
    for (int ch = 0; ch < 8; ++ch) {
        const int d0 = ch << 7;
        __syncthreads();
#pragma unroll
        for (int i = 0; i < 8; ++i) {
            const int u = tid + (i << 8);
            const int row = u >> 5, q = u & 31;
            *(float4*)&e_lds[row * 128 + q * 4] =
                *(const float4*)(E + (size_t)(bb * 64 + row) * 1024 + d0 + q * 4);
        }
        __syncthreads();
        float s[8] = {0.f, 0.f, 0.f, 0.f, 0.f, 0.f, 0.f, 0.f};
        for (int t = 0; t < 64; ++t) {
            const float ev = e_lds[t * 128 + dl];
#pragma unroll
            for (int j = 0; j < 8; ++j) s[j] = fmaf(ev, s_beta[t * 16 + m0 + j], s[j]);
        }
        float4 lo = {s[0], s[1], s[2], s[3]}, hi = {s[4], s[5], s[6], s[7]};
        float* epr = ws + P3_EP + (size_t)p * 16384 + (size_t)(d0 + dl) * 16 + m0;
        *(float4*)epr = lo; *(float4*)(epr + 4) = hi;
#pragma unroll
        for (int j = 0; j < 8; ++j) s2[j] += s[j] * s[j];
    }
#pragma unroll
    for (int j = 0; j < 8; ++j) atomicAdd(&s_eps[m0 + j], s2[j]);
    __syncthreads();
    if (tid < 16) ws[P3_EPN2 + (size_t)p * 16 + tid] = s_eps[tid];
}

// cos2 accumulation into REF. grid 256 = (a, m); 256 threads.
__global__ __launch_bounds__(256)
void tail2_3(const float* __restrict__ Vb, float* __restrict__ ws)
{
    __shared__ float lds_ep[16 * 1024];
    const int tid = threadIdx.x;
    const int L = (int)(blockIdx.x >> 3) + (int)(blockIdx.x & 7) * 32;
    const int a = L >> 4, m = L & 15;
    const int w = tid >> 6, lane = tid & 63;
    for (int idx = tid; idx < 16384; idx += 256) {
        const int bbi = idx >> 10, d = idx & 1023;
        lds_ep[idx] = ws[P3_EP + (size_t)(a * 16 + bbi) * 16384 + (size_t)d * 16 + m];
    }
    __syncthreads();
    for (int i = 0; i < 16; ++i) {
        const int r = m * 64 + w * 16 + i;
        const float* vr = Vb + (size_t)(a * 1024 + r) * 1024;
        float vv[16];
#pragma unroll
        for (int k = 0; k < 16; ++k) vv[k] = vr[lane + (k << 6)];
        const float vn = ws[P3_VN2 + (size_t)a * 1024 + r];
#pragma unroll
        for (int bbi = 0; bbi < 16; ++bbi) {
            float dot = 0.f;
#pragma unroll
            for (int k = 0; k < 16; ++k)
                dot = fmaf(vv[k], lds_ep[bbi * 1024 + lane + (k << 6)], dot);
#pragma unroll
            for (int off = 32; off; off >>= 1) dot += __shfl_xor(dot, off);
            if (lane == 0) {
                const float ep2 = ws[P3_EPN2 + (size_t)(a * 16 + bbi) * 16 + m];
                const float c2 = dot / (sqrtf(vn) * sqrtf(ep2));
                atomicAdd(&ws[P3_REF + (size_t)(a * 16 + bbi) * 16 + m], c2 * (1.0f / 64.0f));
            }
        }
    }
}

// Per-pair S -> exp_S. grid 256 (pairs), 64 threads.
__global__ __launch_bounds__(64)
void pair_score3(float* __restrict__ ws)
{
    const int p = blockIdx.x, bb = p & 15, lane = threadIdx.x;
    const float dp = ws[P3_DP + (size_t)p * 64 + lane];
    const float nq = ws[P3_NSQ + (size_t)p * 64 + lane];
    const float en = ws[P3_EN2 + (size_t)bb * 64 + lane];
    float s1 = dp / (sqrtf(nq) * sqrtf(en));
#pragma unroll
    for (int off = 32; off; off >>= 1) s1 += __shfl_xor(s1, off);
    float s2 = (lane < 16) ? __expf(ws[P3_REF + (size_t)p * 16 + lane]) : 0.f;
#pragma unroll
    for (int off = 32; off; off >>= 1) s2 += __shfl_xor(s2, off);
    if (lane == 0) {
        const float S = logf(s1) / G2 + logf(s2) / G2;
        ws[P3_ES + p] = G3 * __expf(S);
    }
}

// beta regularizer, one block per diagonal pair i. grid 16, 256 threads.
__global__ __launch_bounds__(256)
void reg3(float* __restrict__ ws)
{
    __shared__ float sbeta[1024];
    __shared__ float wsum[4];
    const int tid = threadIdx.x, i = blockIdx.x;
#pragma unroll
    for (int k = 0; k < 4; ++k)
        sbeta[tid + (k << 8)] = ws[P3_BETA + (size_t)(i * 17) * 1024 + tid + (k << 8)];
    __syncthreads();
    float part = 0.f;
#pragma unroll
    for (int ii = 0; ii < 16; ++ii) {
        const int idx = tid + (ii << 8);
        const int t = idx >> 6, s = idx & 63;
        float bt = 0.f, ds = 0.f;
#pragma unroll
        for (int mm = 0; mm < 16; ++mm) {
            bt += sbeta[t * 16 + mm] * sbeta[s * 16 + mm];
            ds += sbeta[s * 16 + mm] * sbeta[s * 16 + mm];
        }
        const float df = bt - ds;
        part += df * df;
    }
#pragma unroll
    for (int off = 32; off; off >>= 1) part += __shfl_xor(part, off);
    if ((tid & 63) == 0) wsum[tid >> 6] = part;
    __syncthreads();
    if (tid == 0)
        ws[P3_RG + i] = sqrtf(wsum[0] + wsum[1] + wsum[2] + wsum[3]);
}

// Final scalar: loss1 + loss2 + reg. grid 1, 256 threads.
__global__ __launch_bounds__(256)
void final3b(const float* __restrict__ ws, float* __restrict__ out)
{
    __shared__ float es[256];
    const int tid = threadIdx.x;
    es[tid] = ws[P3_ES + tid];
    __syncthreads();
    if (tid == 0) {
        float l = 0.f;
        for (int i = 0; i < 16; ++i) {
            float rs = 0.f, cs = 0.f;
            for (int j = 0; j < 16; ++j) { rs += es[i * 16 + j]; cs += es[j * 16 + i]; }
            const float num = es[i * 17];
            l -= num / rs;
            l -= num / cs;
        }
        for (int i = 0; i < 16; ++i) l += ws[P3_RG + i];
        out[0] = l;
    }
}

// ============================ ROUND-2 PATH (fallback, verified) ============================

__global__ __launch_bounds__(256)
void split_kernel(const float* __restrict__ E, const float* __restrict__ Vb,
                  float* __restrict__ ws)
{
    const int tid = threadIdx.x, b = blockIdx.x;
    const int sub = tid >> 5, lane32 = tid & 31;
    const float* src; short* dh; short* dl; float* nout; int row;
    if (b < 2048) {
        row = b * 8 + sub;
        src = Vb + (size_t)row * 1024;
        dh = (short*)(ws + O_VH) + (size_t)row * 1024;
        dl = (short*)(ws + O_VL) + (size_t)row * 1024;
        nout = ws + O_VN2 + row;
    } else {
        row = (b - 2048) * 8 + sub;
        src = E + (size_t)row * 1024;
        dh = (short*)(ws + O_EH) + (size_t)row * 1024;
        dl = (short*)(ws + O_EL) + (size_t)row * 1024;
        nout = ws + O_EN2 + row;
    }
    float nrm = 0.f;
#pragma unroll
    for (int i = 0; i < 8; ++i) {
        const int c = lane32 * 4 + i * 128;
        float4 f = *(const float4*)(src + c);
        short4 hs, ls;
        hs.x = f2bf(f.x); ls.x = f2bf(f.x - bf2f(hs.x));
        hs.y = f2bf(f.y); ls.y = f2bf(f.y - bf2f(hs.y));
        hs.z = f2bf(f.z); ls.z = f2bf(f.z - bf2f(hs.z));
        hs.w = f2bf(f.w); ls.w = f2bf(f.w - bf2f(hs.w));
        *(short4*)(dh + c) = hs;
        *(short4*)(dl + c) = ls;
        nrm += f.x*f.x + f.y*f.y + f.z*f.z + f.w*f.w;
    }
#pragma unroll
    for (int off = 16; off; off >>= 1) nrm += __shfl_xor(nrm, off);
    if (lane32 == 0) *nout = nrm;
}

__global__ __launch_bounds__(512, 2)
void stageA_kernel(float* __restrict__ ws)
{
    __shared__ short sE[2][64 * 32];
    __shared__ short sV[2][1024 * 32];
    __shared__ float sZw[512], sDw[512], s_bnum[1024], s_bsum[16], s_invZ[64];

    const int tid = threadIdx.x;
    const int L = (int)(blockIdx.x >> 3) + (int)(blockIdx.x & 7) * 32;
    const int p = L, a = p >> 4, bb = p & 15;
    const int w = tid >> 6, lane = tid & 63, l31 = lane & 31, h = lane >> 5;

    const short* vhp = (const short*)(ws + O_VH) + (size_t)a * (1024 * 1024);
    const short* vlp = (const short*)(ws + O_VL) + (size_t)a * (1024 * 1024);
    const short* ehp = (const short*)(ws + O_EH) + (size_t)bb * (64 * 1024);
    const short* elp = (const short*)(ws + O_EL) + (size_t)bb * (64 * 1024);
    float* attnp = ws + O_ATTN + (size_t)p * 65536;

    f32x16 acc[2][4] = {};

    for (int kt = 0; kt < 32; ++kt) {
        const int k0 = kt << 5;
        {
            const int pp = tid >> 8, row = (tid >> 2) & 63, q = tid & 3;
            const short* g = pp ? elp : ehp;
            s16x8 dvec = *(const s16x8*)(g + (size_t)row * 1024 + k0 + (q << 3));
            *(s16x8*)&sE[pp][(row << 5) + ((q ^ (row & 3)) << 3)] = dvec;
        }
#pragma unroll
        for (int pp = 0; pp < 2; ++pp) {
            const short* g = pp ? vlp : vhp;
#pragma unroll
            for (int i = 0; i < 8; ++i) {
                const int u = tid + (i << 9);
                const int row = u >> 2, q = u & 3;
                s16x8 dvec = *(const s16x8*)(g + (size_t)row * 1024 + k0 + (q << 3));
                *(s16x8*)&sV[pp][(row << 5) + ((q ^ (row & 3)) << 3)] = dvec;
            }
        }
        __syncthreads();
#pragma unroll
        for (int kk = 0; kk < 2; ++kk) {
            const int unit = (kk << 1) + h;
            s16x8 ah[2], al[2];
#pragma unroll
            for (int rs = 0; rs < 2; ++rs) {
                const int row = (rs << 5) + l31;
                const int off = (row << 5) + ((unit ^ (row & 3)) << 3);
                ah[rs] = *(const s16x8*)&sE[0][off];
                al[rs] = *(const s16x8*)&sE[1][off];
            }
#pragma unroll
            for (int cs = 0; cs < 4; ++cs) {
                const int r = (w << 7) + (cs << 5) + l31;
                const int off = (r << 5) + ((unit ^ (r & 3)) << 3);
                const s16x8 bh = *(const s16x8*)&sV[0][off];
                const s16x8 bl = *(const s16x8*)&sV[1][off];
#pragma unroll
                for (int rs = 0; rs < 2; ++rs) {
                    acc[rs][cs] = __builtin_amdgcn_mfma_f32_32x32x16_bf16(ah[rs], bh, acc[rs][cs], 0, 0, 0);
                    acc[rs][cs] = __builtin_amdgcn_mfma_f32_32x32x16_bf16(ah[rs], bl, acc[rs][cs], 0, 0, 0);
                    acc[rs][cs] = __builtin_amdgcn_mfma_f32_32x32x16_bf16(al[rs], bh, acc[rs][cs], 0, 0, 0);
                }
            }
        }
        __syncthreads();
    }

    float cmax[4], cinv[4];
#pragma unroll
    for (int cs = 0; cs < 4; ++cs) {
        float mx = -1e30f;
#pragma unroll
        for (int rs = 0; rs < 2; ++rs)
#pragma unroll
            for (int q = 0; q < 16; ++q) mx = fmaxf(mx, acc[rs][cs][q]);
        mx = fmaxf(mx, __shfl_xor(mx, 32));
        float sm = 0.f;
#pragma unroll
        for (int rs = 0; rs < 2; ++rs)
#pragma unroll
            for (int q = 0; q < 16; ++q) sm += __expf(acc[rs][cs][q] - mx);
        sm += __shfl_xor(sm, 32);
        cmax[cs] = mx; cinv[cs] = 1.0f / sm;
    }
#pragma unroll
    for (int rs = 0; rs < 2; ++rs) {
#pragma unroll
        for (int q = 0; q < 16; ++q) {
            float zp = 0.f, dp = 0.f, bn0 = 0.f, bn1 = 0.f;
#pragma unroll
            for (int cs = 0; cs < 4; ++cs) {
                const float sim = acc[rs][cs][q];
                const float ns = __expf(sim - cmax[cs]) * cinv[cs];
                const float se = __expf(ns);
                float w5 = se * se; w5 = w5 * w5; w5 *= se;
                zp += w5; dp += w5 * sim;
                if (cs < 2) bn0 += se; else bn1 += se;
                acc[rs][cs][q] = w5;
            }
#pragma unroll
            for (int off = 16; off; off >>= 1) {
                zp  += __shfl_xor(zp, off);
                dp  += __shfl_xor(dp, off);
                bn0 += __shfl_xor(bn0, off);
                bn1 += __shfl_xor(bn1, off);
            }
            if (l31 == 0) {
                const int t = (rs << 5) + (q & 3) + ((q >> 2) << 3) + (h << 2);
                sZw[(w << 6) + t] = zp;
                sDw[(w << 6) + t] = dp;
                s_bnum[(t << 4) + (w << 1)]     = bn0;
                s_bnum[(t << 4) + (w << 1) + 1] = bn1;
            }
        }
    }
    __syncthreads();
    if (tid < 64) {
        float Z = 0.f, dv = 0.f;
#pragma unroll
        for (int ww = 0; ww < 8; ++ww) { Z += sZw[(ww << 6) + tid]; dv += sDw[(ww << 6) + tid]; }
        s_invZ[tid] = 1.0f / Z;
        ws[O_DOTVE + (size_t)p * 64 + tid] = dv / Z;
        ws[O_NSQ   + (size_t)p * 64 + tid] = 0.f;
    }
    if (tid >= 64 && tid < 80) ws[O_REF + (size_t)p * 16 + (tid - 64)] = 0.f;
    if (tid >= 128 && tid < 144) {
        float s = 0.f;
        for (int t = 0; t < 64; ++t) s += s_bnum[(t << 4) + (tid - 128)];
        s_bsum[tid - 128] = s;
    }
    __syncthreads();
    for (int idx = tid; idx < 1024; idx += 512)
        ws[O_BETA + (size_t)p * 1024 + idx] = s_bnum[idx] / s_bsum[idx & 15];
#pragma unroll
    for (int rs = 0; rs < 2; ++rs)
#pragma unroll
        for (int q = 0; q < 16; ++q) {
            const int t = (rs << 5) + (q & 3) + ((q >> 2) << 3) + (h << 2);
            const float iz = s_invZ[t];
#pragma unroll
            for (int cs = 0; cs < 4; ++cs) {
                const int r = (w << 7) + (cs << 5) + l31;
                attnp[(size_t)t * 1024 + r] = acc[rs][cs][q] * iz;
            }
        }
}

__global__ __launch_bounds__(256, 2)
void stageB_kernel(float* __restrict__ ws)
{
    __shared__ short sA[2][128 * 32];
    __shared__ short sB[2][128 * 32];
    const int tid = threadIdx.x;
    const int L = (int)(blockIdx.x >> 3) + (int)(blockIdx.x & 7) * 128;
    const int a = L >> 6, tile = L & 63, tm = tile >> 3, tn = tile & 7;
    const int lane = tid & 63, l31 = lane & 31, h = lane >> 5;
    const int w = tid >> 6;
    const int rw = w & 1, cw = w >> 1;
    const float* attn_a = ws + O_ATTN + (size_t)a * 1048576;
    const short* vhp = (const short*)(ws + O_VH) + (size_t)a * (1024 * 1024);
    const short* vlp = (const short*)(ws + O_VL) + (size_t)a * (1024 * 1024);
    const int dqt = tid & 31, rqt = tid >> 5;
    f32x16 acc[2][2] = {};

    for (int rk = 0; rk < 32; ++rk) {
        const int r0 = rk << 5;
#pragma unroll
        for (int i = 0; i < 4; ++i) {
            const int u = tid + (i << 8);
            const int row = u >> 3, q = u & 7;
            const float4 f = *(const float4*)(attn_a + (size_t)(tm * 128 + row) * 1024 + r0 + (q << 2));
            short4 hs, ls;
            hs.x = f2bf(f.x); ls.x = f2bf(f.x - bf2f(hs.x));
            hs.y = f2bf(f.y); ls.y = f2bf(f.y - bf2f(hs.y));
            hs.z = f2bf(f.z); ls.z = f2bf(f.z - bf2f(hs.z));
            hs.w = f2bf(f.w); ls.w = f2bf(f.w - bf2f(hs.w));
            const int off = (row << 5) + ((((q >> 1) ^ (row & 3))) << 3) + ((q & 1) << 2);
            *(short4*)&sA[0][off] = hs;
            *(short4*)&sA[1][off] = ls;
        }
#pragma unroll
        for (int pp = 0; pp < 2; ++pp) {
            const short* g = pp ? vlp : vhp;
            short4 in0 = *(const short4*)(g + (size_t)(r0 + rqt * 4 + 0) * 1024 + tn * 128 + dqt * 4);
            short4 in1 = *(const short4*)(g + (size_t)(r0 + rqt * 4 + 1) * 1024 + tn * 128 + dqt * 4);
            short4 in2 = *(const short4*)(g + (size_t)(r0 + rqt * 4 + 2) * 1024 + tn * 128 + dqt * 4);
            short4 in3 = *(const short4*)(g + (size_t)(r0 + rqt * 4 + 3) * 1024 + tn * 128 + dqt * 4);
            short4 o0 = {in0.x, in1.x, in2.x, in3.x};
            short4 o1 = {in0.y, in1.y, in2.y, in3.y};
            short4 o2 = {in0.z, in1.z, in2.z, in3.z};
            short4 o3 = {in0.w, in1.w, in2.w, in3.w};
            {   const int d = dqt * 4 + 0;
                *(short4*)&sB[pp][(d << 5) + (((rqt >> 1) ^ ((d >> 2) & 3)) << 3) + ((rqt & 1) << 2)] = o0; }
            {   const int d = dqt * 4 + 1;
                *(short4*)&sB[pp][(d << 5) + (((rqt >> 1) ^ ((d >> 2) & 3)) << 3) + ((rqt & 1) << 2)] = o1; }
            {   const int d = dqt * 4 + 2;
                *(short4*)&sB[pp][(d << 5) + (((rqt >> 1) ^ ((d >> 2) & 3)) << 3) + ((rqt & 1) << 2)] = o2; }
            {   const int d = dqt * 4 + 3;
                *(short4*)&sB[pp][(d << 5) + (((rqt >> 1) ^ ((d >> 2) & 3)) << 3) + ((rqt & 1) << 2)] = o3; }
        }
        __syncthreads();
#pragma unroll
        for (int kk = 0; kk < 2; ++kk) {
            const int unit = (kk << 1) + h;
            s16x8 ah[2], al[2];
#pragma unroll
            for (int rs = 0; rs < 2; ++rs) {
                const int row = rw * 64 + rs * 32 + l31;
                const int off = (row << 5) + ((unit ^ (row & 3)) << 3);
                ah[rs] = *(const s16x8*)&sA[0][off];
                al[rs] = *(const s16x8*)&sA[1][off];
            }
#pragma unroll
            for (int cs = 0; cs < 2; ++cs) {
                const int d = cw * 64 + cs * 32 + l31;
                const int off = (d << 5) + ((unit ^ ((d >> 2) & 3)) << 3);
                const s16x8 bh = *(const s16x8*)&sB[0][off];
                const s16x8 bl = *(const s16x8*)&sB[1][off];
#pragma unroll
                for (int rs = 0; rs < 2; ++rs) {
                    acc[rs][cs] = __builtin_amdgcn_mfma_f32_32x32x16_bf16(ah[rs], bh, acc[rs][cs], 0, 0, 0);
                    acc[rs][cs] = __builtin_amdgcn_mfma_f32_32x32x16_bf16(ah[rs], bl, acc[rs][cs], 0, 0, 0);
                    acc[rs][cs] = __builtin_amdgcn_mfma_f32_32x32x16_bf16(al[rs], bh, acc[rs][cs], 0, 0, 0);
                }
            }
        }
        __syncthreads();
    }
#pragma unroll
    for (int rs = 0; rs < 2; ++rs) {
#pragma unroll
        for (int q = 0; q < 16; ++q) {
            float x = acc[rs][0][q] * acc[rs][0][q] + acc[rs][1][q] * acc[rs][1][q];
#pragma unroll
            for (int off = 16; off; off >>= 1) x += __shfl_xor(x, off);
            if (l31 == 0) {
                const int t_local = rw * 64 + rs * 32 + (q & 3) + ((q >> 2) << 3) + (h << 2);
                atomicAdd(&ws[O_NSQ + (size_t)a * 1024 + tm * 128 + t_local], x);
            }
        }
    }
}

__global__ __launch_bounds__(256)
void tail1_kernel(const float* __restrict__ E, float* __restrict__ ws)
{
    __shared__ float s_beta[1024];
    __shared__ float e_lds[64 * 128];
    __shared__ float s_eps[16];
    const int tid = threadIdx.x, p = blockIdx.x, bb = p & 15;
#pragma unroll
    for (int i = 0; i < 4; ++i)
        s_beta[tid + (i << 8)] = ws[O_BETA + (size_t)p * 1024 + tid + (i << 8)];
    if (tid < 16) s_eps[tid] = 0.f;
    const int dl = tid >> 1, m0 = (tid & 1) * 8;
    float s2[8] = {0.f,0.f,0.f,0.f,0.f,0.f,0.f,0.f};
    for (int ch = 0; ch < 8; ++ch) {
        const int d0 = ch << 7;
        __syncthreads();
#pragma unroll
        for (int i = 0; i < 8; ++i) {
            const int u = tid + (i << 8);
            const int row = u >> 5, q = u & 31;
            *(float4*)&e_lds[row * 128 + q * 4] =
                *(const float4*)(E + (size_t)(bb * 64 + row) * 1024 + d0 + q * 4);
        }
        __syncthreads();
        float s[8] = {0.f,0.f,0.f,0.f,0.f,0.f,0.f,0.f};
        for (int t = 0; t < 64; ++t) {
            const float ev = e_lds[t * 128 + dl];
#pragma unroll
            for (int j = 0; j < 8; ++j) s[j] = fmaf(ev, s_beta[t * 16 + m0 + j], s[j]);
        }
        float4 lo = {s[0], s[1], s[2], s[3]}, hi = {s[4], s[5], s[6], s[7]};
        float* epr = ws + O_EP + (size_t)p * 16384 + (size_t)(d0 + dl) * 16 + m0;
        *(float4*)epr = lo; *(float4*)(epr + 4) = hi;
#pragma unroll
        for (int j = 0; j < 8; ++j) s2[j] += s[j] * s[j];
    }
#pragma unroll
    for (int j = 0; j < 8; ++j) atomicAdd(&s_eps[m0 + j], s2[j]);
    __syncthreads();
    if (tid < 16) ws[O_EPN2 + (size_t)p * 16 + tid] = s_eps[tid];
}

__global__ __launch_bounds__(256)
void tail2_kernel(const float* __restrict__ Vb, float* __restrict__ ws)
{
    __shared__ float lds_ep[16 * 1024];
    const int tid = threadIdx.x;
    const int L = (int)(blockIdx.x >> 3) + (int)(blockIdx.x & 7) * 32;
    const int a = L >> 4, m = L & 15;
    const int w = tid >> 6, lane = tid & 63;
    for (int idx = tid; idx < 16384; idx += 256) {
        const int bbi = idx >> 10, d = idx & 1023;
        lds_ep[idx] = ws[O_EP + (size_t)(a * 16 + bbi) * 16384 + (size_t)d * 16 + m];
    }
    __syncthreads();
    for (int i = 0; i < 16; ++i) {
        const int r = m * 64 + w * 16 + i;
        const float* vr = Vb + (size_t)(a * 1024 + r) * 1024;
        float vv[16];
#pragma unroll
        for (int k = 0; k < 16; ++k) vv[k] = vr[lane + (k << 6)];
        const float vn = ws[O_VN2 + a * 1024 + r];
#pragma unroll
        for (int bbi = 0; bbi < 16; ++bbi) {
            float dot = 0.f;
#pragma unroll
            for (int k = 0; k < 16; ++k) dot = fmaf(vv[k], lds_ep[bbi * 1024 + lane + (k << 6)], dot);
#pragma unroll
            for (int off = 32; off; off >>= 1) dot += __shfl_xor(dot, off);
            if (lane == 0) {
                const float ep2 = ws[O_EPN2 + (size_t)(a * 16 + bbi) * 16 + m];
                const float c2 = dot / (sqrtf(vn) * sqrtf(ep2));
                atomicAdd(&ws[O_REF + (size_t)(a * 16 + bbi) * 16 + m], c2 * (1.0f / 64.0f));
            }
        }
    }
}

__global__ __launch_bounds__(256)
void finalize2_kernel(const float* __restrict__ ws, float* __restrict__ out)
{
    __shared__ float s_es[256];
    __shared__ float sbeta[1024];
    __shared__ float s_acc[256];
    __shared__ float s_out[2];
    const int tid = threadIdx.x;
    {
        const int p = tid, bb = p & 15;
        float s1 = 0.f;
        for (int t = 0; t < 64; ++t) {
            const float dv = ws[O_DOTVE + (size_t)p * 64 + t];
            const float nq = ws[O_NSQ + (size_t)p * 64 + t];
            const float en = ws[O_EN2 + bb * 64 + t];
            s1 += dv / (sqrtf(nq) * sqrtf(en));
        }
        float s2 = 0.f;
        for (int mm = 0; mm < 16; ++mm) s2 += __expf(ws[O_REF + (size_t)p * 16 + mm]);
        const float S = logf(s1) / G2 + logf(s2) / G2;
        s_es[p] = G3 * __expf(S);
    }
    __syncthreads();
    if (tid == 0) {
        float l = 0.f;
        for (int i = 0; i < 16; ++i) {
            float rs = 0.f, cs = 0.f;
            for (int j = 0; j < 16; ++j) { rs += s_es[i * 16 + j]; cs += s_es[j * 16 + i]; }
            const float num = s_es[i * 16 + i];
            l -= num / rs;
            l -= num / cs;
        }
        s_out[0] = l; s_out[1] = 0.f;
    }
    for (int i = 0; i < 16; ++i) {
        for (int idx = tid; idx < 1024; idx += 256)
            sbeta[idx] = ws[O_BETA + (size_t)(i * 17) * 1024 + idx];
        __syncthreads();
        float part = 0.f;
        for (int idx = tid; idx < 4096; idx += 256) {
            const int t = idx >> 6, s = idx & 63;
            float bt = 0.f, ds = 0.f;
            for (int mm = 0; mm < 16; ++mm) {
                bt += sbeta[t * 16 + mm] * sbeta[s * 16 + mm];
                ds += sbeta[s * 16 + mm] * sbeta[s * 16 + mm];
            }
            const float df = bt - ds;
            part += df * df;
        }
        s_acc[tid] = part;
        __syncthreads();
        if (tid == 0) {
            float tot = 0.f;
            for (int j = 0; j < 256; ++j) tot += s_acc[j];
            s_out[1] += sqrtf(tot);
        }
        __syncthreads();
    }
    if (tid == 0) out[0] = s_out[0] + s_out[1];
}

// ============================ launch ============================

extern "C" void kernel_launch(void* const* d_in, const int* in_sizes, int n_in,
                              void* d_out, int out_size, void* d_ws, size_t ws_size,
                              hipStream_t stream)
{
    const float* E  = (const float*)d_in[0];
    const float* Vb = (const float*)d_in[1];
    float* ws  = (float*)d_ws;
    float* out = (float*)d_out;

    if (ws_size >= (size_t)P3_TOTAL * 4) {
        hipMemsetAsync((char*)d_ws + P3_ACC * 4, 0, P3_ACCN * 4, stream);
        pack_v3<<<dim3(4096), dim3(256), 0, stream>>>(Vb, ws);
        pack_e3<<<dim3(16), dim3(512), 0, stream>>>(E, ws);
        stageA3<<<dim3(512), dim3(512), 0, stream>>>(ws);
        stageB3<<<dim3(512), dim3(512), 0, stream>>>(ws);
        tail1_3<<<dim3(256), dim3(256), 0, stream>>>(E, ws);
        tail2_3<<<dim3(256), dim3(256), 0, stream>>>(Vb, ws);
        pair_score3<<<dim3(256), dim3(64), 0, stream>>>(ws);
        reg3<<<dim3(16), dim3(256), 0, stream>>>(ws);
        final3b<<<dim3(1), dim3(256), 0, stream>>>(ws, out);
        return;
    }

    // fallback: round-2 verified path
    split_kernel<<<dim3(2176), dim3(256), 0, stream>>>(E, Vb, ws);
    stageA_kernel<<<dim3(256), dim3(512), 0, stream>>>(ws);
    stageB_kernel<<<dim3(1024), dim3(256), 0, stream>>>(ws);
    tail1_kernel<<<dim3(256), dim3(256), 0, stream>>>(E, ws);
    tail2_kernel<<<dim3(256), dim3(256), 0, stream>>>(Vb, ws);
    finalize2_kernel<<<dim3(1), dim3(256), 0, stream>>>(ws, out);
}